// Round 18
// baseline (1998.009 us; speedup 1.0000x reference)
//
#include <hip/hip_runtime.h>
#include <stdint.h>

#define TT 128
#define BB 128
#define DD 300
#define EE 1024
#define GG 900
#define NMU 1008
#define ASP 500
#define KP 608

#define OUT_SLOG 131072
#define OUT_ACT  163840
#define OUT_LOGP 196608

typedef unsigned int u32x4 __attribute__((ext_vector_type(4)));

// ---------------- threefry2x32 (JAX, 20 rounds) ----------------
__host__ __device__ static inline uint32_t rotl32(uint32_t x, int r){
  return (x << r) | (x >> (32 - r));
}

__host__ __device__ static inline void tf2x32(uint32_t k0, uint32_t k1,
                                              uint32_t x0, uint32_t x1,
                                              uint32_t* o0, uint32_t* o1){
  uint32_t ks2 = k0 ^ k1 ^ 0x1BD11BDAu;
#define TFR(r) { x0 += x1; x1 = rotl32(x1, r); x1 ^= x0; }
  x0 += k0; x1 += k1;
  TFR(13) TFR(15) TFR(26) TFR(6)
  x0 += k1; x1 += ks2 + 1u;
  TFR(17) TFR(29) TFR(16) TFR(24)
  x0 += ks2; x1 += k0 + 2u;
  TFR(13) TFR(15) TFR(26) TFR(6)
  x0 += k0; x1 += k1 + 3u;
  TFR(17) TFR(29) TFR(16) TFR(24)
  x0 += k1; x1 += ks2 + 4u;
  TFR(13) TFR(15) TFR(26) TFR(6)
  x0 += ks2; x1 += k0 + 5u;
#undef TFR
  *o0 = x0; *o1 = x1;
}

__device__ static inline uint32_t rng32(uint32_t k0, uint32_t k1, uint32_t idx){
  uint32_t a, b;
  tf2x32(k0, k1, 0u, idx, &a, &b);
  return a ^ b;
}

__device__ static inline float u01(uint32_t bits){
  return __uint_as_float((bits >> 9) | 0x3f800000u) - 1.0f;
}

__device__ static inline float jgumbel(uint32_t k0, uint32_t k1, uint32_t idx){
  float u = u01(rng32(k0, k1, idx));
  float l1 = logf(u + 1e-20f);
  return -logf(-l1 + 1e-20f);
}

__device__ static inline float erfinv32(float x){   // XLA ErfInv32 (Giles)
  float w = -log1pf(-x * x);
  float p;
  if (w < 5.0f){
    w = w - 2.5f;
    p = 2.81022636e-08f;
    p = 3.43273939e-07f  + p * w;
    p = -3.5233877e-06f  + p * w;
    p = -4.39150654e-06f + p * w;
    p = 0.00021858087f   + p * w;
    p = -0.00125372503f  + p * w;
    p = -0.00417768164f  + p * w;
    p = 0.246640727f     + p * w;
    p = 1.50140941f      + p * w;
  } else {
    w = sqrtf(w) - 3.0f;
    p = -0.000200214257f;
    p = 0.000100950558f  + p * w;
    p = 0.00134934322f   + p * w;
    p = -0.00367342844f  + p * w;
    p = 0.00573950773f   + p * w;
    p = -0.0076224613f   + p * w;
    p = 0.00943887047f   + p * w;
    p = 1.00167406f      + p * w;
    p = 2.83297682f      + p * w;
  }
  return p * x;
}

__device__ static inline float jnormal(uint32_t k0, uint32_t k1, uint32_t idx){
  float u = u01(rng32(k0, k1, idx));
  const float lo = -0.99999994f;
  float v = u * 2.0f + lo;
  v = fmaxf(lo, v);
  return 1.41421356237f * erfinv32(v);
}

__device__ static inline float jsigmoid(float x){
  return 1.0f / (1.0f + expf(-x));
}

__device__ static inline unsigned short f2bf(float f){   // RNE f32->bf16
  uint32_t u = __float_as_uint(f);
  uint32_t r = (u + 0x7fffu + ((u >> 16) & 1u)) >> 16;
  return (unsigned short)r;
}
__device__ static inline float bf2f(unsigned short h){
  return __uint_as_float((uint32_t)h << 16);
}

// ---- LLC-coherent (cross-XCD) memory ops: sc0 sc1 = bypass L1+L2 ----
__device__ static inline u32x4 load_b128_llc(const void* p){
  u32x4 r;
  asm volatile("global_load_dwordx4 %0, %1, off sc0 sc1"
               : "=v"(r) : "v"(p) : "memory");
  return r;
}
__device__ static inline void store_b128_llc(void* p, u32x4 v){
  asm volatile("global_store_dwordx4 %0, %1, off sc0 sc1"
               :: "v"(p), "v"(v) : "memory");
}
__device__ static inline unsigned poll_u32_llc(const void* p){
  unsigned r;
  asm volatile("global_load_dword %0, %1, off sc0 sc1\n\ts_waitcnt vmcnt(0)"
               : "=v"(r) : "v"(p) : "memory");
  return r;
}
__device__ static inline void store_u32_llc(void* p, unsigned v){
  asm volatile("global_store_dword %0, %1, off sc0 sc1"
               :: "v"(p), "v"(v) : "memory");
}

#define WAITV(N) do{ asm volatile("s_waitcnt vmcnt(" #N ")" ::: "memory"); \
                     __builtin_amdgcn_sched_barrier(0); }while(0)

// ---------------- GEMM1: gi_all[r=(t*BB+b)][900] = x@Wih_c^T + bih (fp32) -----
#define FMA4(ACC, S, B) { ACC.x += (S)*(B).x; ACC.y += (S)*(B).y; \
                          ACC.z += (S)*(B).z; ACC.w += (S)*(B).w; }

__global__ __launch_bounds__(256) void k_gemm_gi(
    const float* __restrict__ X, const float* __restrict__ W,
    const float* __restrict__ bias, float* __restrict__ C)
{
  __shared__ float As[16][132];
  __shared__ float Bs[16][68];
  const int tid = threadIdx.x;
  const int rbase = blockIdx.y * 128;
  const int cbase = blockIdx.x * 64;
  const int tx = tid & 15, ty = tid >> 4;
  const int sr = tid >> 2, sq = tid & 3;
  const int wj = cbase + sr;

  float4 acc[8];
#pragma unroll
  for (int i = 0; i < 8; ++i) acc[i] = (float4){0,0,0,0};

  for (int k0 = 0; k0 < 304; k0 += 16){
    const int k = k0 + sq * 4;
#pragma unroll
    for (int i = 0; i < 2; ++i){
      const int row = sr + i * 64;
      const int rg = rbase + row;
      float4 va = {0,0,0,0};
      if (k < DD) va = *(const float4*)(X + ((long)(rg & 127) * TT + (rg >> 7)) * DD + k);
      As[sq*4+0][row] = va.x; As[sq*4+1][row] = va.y;
      As[sq*4+2][row] = va.z; As[sq*4+3][row] = va.w;
    }
    {
      float4 vb = {0,0,0,0};
      if (k < DD && wj < GG) vb = *(const float4*)(W + (long)wj * DD + k);
      Bs[sq*4+0][sr] = vb.x; Bs[sq*4+1][sr] = vb.y;
      Bs[sq*4+2][sr] = vb.z; Bs[sq*4+3][sr] = vb.w;
    }
    __syncthreads();
#pragma unroll
    for (int kk = 0; kk < 16; ++kk){
      const float4 b  = *(const float4*)&Bs[kk][tx * 4];
      const float4 a0 = *(const float4*)&As[kk][ty * 8];
      const float4 a1 = *(const float4*)&As[kk][ty * 8 + 4];
      FMA4(acc[0], a0.x, b); FMA4(acc[1], a0.y, b);
      FMA4(acc[2], a0.z, b); FMA4(acc[3], a0.w, b);
      FMA4(acc[4], a1.x, b); FMA4(acc[5], a1.y, b);
      FMA4(acc[6], a1.z, b); FMA4(acc[7], a1.w, b);
    }
    __syncthreads();
  }
  const int ci = cbase + tx * 4;
  float bv[4];
#pragma unroll
  for (int j = 0; j < 4; ++j) bv[j] = (ci + j < GG) ? bias[ci + j] : 0.0f;
#pragma unroll
  for (int i = 0; i < 8; ++i){
    const int r = rbase + ty * 8 + i;
    float vals[4] = {acc[i].x + bv[0], acc[i].y + bv[1],
                     acc[i].z + bv[2], acc[i].w + bv[3]};
    float* crow = C + (long)r * GG;
    if (ci + 3 < GG){
      float4 st = {vals[0], vals[1], vals[2], vals[3]};
      *(float4*)(crow + ci) = st;
    } else {
#pragma unroll
      for (int j = 0; j < 4; ++j) if (ci + j < GG) crow[ci + j] = vals[j];
    }
  }
}

// ---------------- split-bf16 conversions for mu GEMM ----------------
__global__ __launch_bounds__(256) void k_cvt_Amu(
    const float* __restrict__ X, const float* __restrict__ HX,
    unsigned short* __restrict__ Ah, unsigned short* __restrict__ Al)
{
  const long i = (long)blockIdx.x * 256 + threadIdx.x;   // 16384*152 groups
  const int r = (int)(i / 152), g = (int)(i - (long)r * 152);
  const int k = g * 4;
  const int b = r & 127, t = r >> 7;
  float4 v = {0,0,0,0};
  if (k < 300)      v = *(const float4*)(X + ((long)b * TT + t) * DD + k);
  else if (k < 600) v = *(const float4*)(HX + (long)r * DD + (k - 300));
  float vv[4] = {fmaxf(v.x,0.f), fmaxf(v.y,0.f), fmaxf(v.z,0.f), fmaxf(v.w,0.f)};
  unsigned short hi[4], lo[4];
#pragma unroll
  for (int j = 0; j < 4; ++j){
    hi[j] = f2bf(vv[j]);
    lo[j] = f2bf(vv[j] - bf2f(hi[j]));
  }
  const long off = (long)r * KP + k;
  *(uint2*)(Ah + off) = *(const uint2*)hi;
  *(uint2*)(Al + off) = *(const uint2*)lo;
}

__global__ __launch_bounds__(256) void k_cvt_Wmu(
    const float* __restrict__ Wmu, const float* __restrict__ Wlv,
    unsigned short* __restrict__ Wh, unsigned short* __restrict__ Wl)
{
  const long i = (long)blockIdx.x * 256 + threadIdx.x;   // 1024*152 groups
  const int r = (int)(i / 152), g = (int)(i - (long)r * 152);
  const int k = g * 4;
  float4 v = {0,0,0,0};
  if (k < 600){
    if (r < 1000)      v = *(const float4*)(Wmu + (long)r * 600 + k);
    else if (r < 1002) v = *(const float4*)(Wlv + (long)(r - 1000) * 600 + k);
  }
  float vv[4] = {v.x, v.y, v.z, v.w};
  unsigned short hi[4], lo[4];
#pragma unroll
  for (int j = 0; j < 4; ++j){
    hi[j] = f2bf(vv[j]);
    lo[j] = f2bf(vv[j] - bf2f(hi[j]));
  }
  const long off = (long)r * KP + k;
  *(uint2*)(Wh + off) = *(const uint2*)hi;
  *(uint2*)(Wl + off) = *(const uint2*)lo;
}

__global__ __launch_bounds__(256) void k_bias_mu(
    const float* __restrict__ bmu, const float* __restrict__ blv,
    float* __restrict__ bias)
{
  const int i = blockIdx.x * 256 + threadIdx.x;
  if (i < 1024){
    float v = 0.0f;
    if (i < 1000) v = bmu[i];
    else if (i < 1002) v = blv[i - 1000];
    bias[i] = v;
  }
}

// ---------------- mu GEMM: split-bf16 4-term MFMA, 128x64 tiles ----------------
__global__ __launch_bounds__(256) void k_gemm_mf(
    const unsigned short* __restrict__ Ah, const unsigned short* __restrict__ Al,
    const unsigned short* __restrict__ Bh, const unsigned short* __restrict__ Bl,
    const float* __restrict__ bias, float* __restrict__ C)
{
  __shared__ __align__(16) unsigned short sAh[128][40], sAl[128][40];
  __shared__ __align__(16) unsigned short sBh[64][40], sBl[64][40];
  const int tid = threadIdx.x;
  const int cbase = blockIdx.x * 64, rbase = blockIdx.y * 128;
  const int wave = tid >> 6, wm = wave >> 1, wn = wave & 1;
  const int lane = tid & 63, lo = lane & 15, hi4 = lane >> 4;

  using frag = __attribute__((ext_vector_type(8))) short;
  using f32x4 = __attribute__((ext_vector_type(4))) float;
  f32x4 acc[4][2];
#pragma unroll
  for (int a = 0; a < 4; ++a)
#pragma unroll
    for (int c = 0; c < 2; ++c) acc[a][c] = (f32x4){0.f,0.f,0.f,0.f};

  const int arow = tid >> 1, akh = (tid & 1) * 16;
  const int brow = tid >> 2, bkh = (tid & 3) * 8;

  for (int kb = 0; kb < 19; ++kb){
    const int k0 = kb * 32;
    __syncthreads();
    {
      const unsigned short* pa = Ah + (long)(rbase + arow) * KP + k0 + akh;
      *(uint4*)&sAh[arow][akh]     = *(const uint4*)pa;
      *(uint4*)&sAh[arow][akh + 8] = *(const uint4*)(pa + 8);
      const unsigned short* pl = Al + (long)(rbase + arow) * KP + k0 + akh;
      *(uint4*)&sAl[arow][akh]     = *(const uint4*)pl;
      *(uint4*)&sAl[arow][akh + 8] = *(const uint4*)(pl + 8);
      *(uint4*)&sBh[brow][bkh] = *(const uint4*)(Bh + (long)(cbase + brow) * KP + k0 + bkh);
      *(uint4*)&sBl[brow][bkh] = *(const uint4*)(Bl + (long)(cbase + brow) * KP + k0 + bkh);
    }
    __syncthreads();
    frag bh0 = *(const frag*)&sBh[wn*32 + lo][hi4*8];
    frag bh1 = *(const frag*)&sBh[wn*32 + 16 + lo][hi4*8];
    frag bl0 = *(const frag*)&sBl[wn*32 + lo][hi4*8];
    frag bl1 = *(const frag*)&sBl[wn*32 + 16 + lo][hi4*8];
#pragma unroll
    for (int fr = 0; fr < 4; ++fr){
      frag ah = *(const frag*)&sAh[wm*64 + fr*16 + lo][hi4*8];
      frag al = *(const frag*)&sAl[wm*64 + fr*16 + lo][hi4*8];
      acc[fr][0] = __builtin_amdgcn_mfma_f32_16x16x32_bf16(ah, bh0, acc[fr][0], 0, 0, 0);
      acc[fr][0] = __builtin_amdgcn_mfma_f32_16x16x32_bf16(al, bh0, acc[fr][0], 0, 0, 0);
      acc[fr][0] = __builtin_amdgcn_mfma_f32_16x16x32_bf16(ah, bl0, acc[fr][0], 0, 0, 0);
      acc[fr][0] = __builtin_amdgcn_mfma_f32_16x16x32_bf16(al, bl0, acc[fr][0], 0, 0, 0);
      acc[fr][1] = __builtin_amdgcn_mfma_f32_16x16x32_bf16(ah, bh1, acc[fr][1], 0, 0, 0);
      acc[fr][1] = __builtin_amdgcn_mfma_f32_16x16x32_bf16(al, bh1, acc[fr][1], 0, 0, 0);
      acc[fr][1] = __builtin_amdgcn_mfma_f32_16x16x32_bf16(ah, bl1, acc[fr][1], 0, 0, 0);
      acc[fr][1] = __builtin_amdgcn_mfma_f32_16x16x32_bf16(al, bl1, acc[fr][1], 0, 0, 0);
    }
  }
#pragma unroll
  for (int fr = 0; fr < 4; ++fr)
#pragma unroll
    for (int fc = 0; fc < 2; ++fc){
      const int col = cbase + wn*32 + fc*16 + lo;
      if (col < NMU){
        const float bv = bias[col];
        const int r0 = rbase + wm*64 + fr*16 + hi4*4;
#pragma unroll
        for (int j = 0; j < 4; ++j)
          C[(long)(r0 + j) * NMU + col] = acc[fr][fc][j] + bv;
      }
    }
}

// ---------------- stage-1 W pack: 3-way bf16 split, fragment-ready ----------
__global__ __launch_bounds__(256) void k_pack_w3(
    const float* __restrict__ W, unsigned short* __restrict__ Wb3)
{
  const int g = blockIdx.x * 256 + threadIdx.x;   // 16*3*64*80
  if (g >= 245760) return;
  const int k4 = g % 80;
  const int r2 = g / 80;
  const int row = r2 % 64;
  const int r3 = r2 / 64;
  const int s = r3 % 3;
  const int js = r3 / 3;
  const int wid = (js < 15) ? 19 : 15;
  const int jj0 = js * 19;
  unsigned short o4[4];
#pragma unroll
  for (int e = 0; e < 4; ++e){
    const int k = k4 * 4 + e;
    float v = 0.0f;
    if (row < 3 * wid && k < 300){
      const int gate = row / wid, col = row - gate * wid;
      v = W[(long)(gate * 300 + jj0 + col) * 300 + k];
    }
    const unsigned short w1 = f2bf(v);
    const float r1 = v - bf2f(w1);
    const unsigned short w2 = f2bf(r1);
    const float r2f = r1 - bf2f(w2);
    const unsigned short w3 = f2bf(r2f);
    o4[e] = (s == 0) ? w1 : ((s == 1) ? w2 : w3);
  }
  *(uint2*)(Wb3 + ((long)(js * 3 + s) * 64 + row) * 320 + k4 * 4) = *(const uint2*)o4;
}

// ---------------- stage-1: 256 blocks = 16 batch-groups(8 rows) x 16 jj-slices --
#define S1PAD 304

__global__ __launch_bounds__(256, 1) void k_stage1(
    const unsigned short* __restrict__ Wb3, const float* __restrict__ bhh,
    const float* __restrict__ gi_all, float* __restrict__ hx_all,
    float* __restrict__ hex, unsigned int* __restrict__ flagsA)
{
  __shared__ __align__(16) float hs[8][S1PAD];
  __shared__ __align__(16) unsigned short hb[3][8][320];
  __shared__ float ghs[512];
  const int tid = threadIdx.x;
  const int bid = blockIdx.x;
  const int bq = bid >> 4, js = bid & 15;
  const int b0 = bq * 8;
  const int wid = (js < 15) ? 19 : 15;
  const int jj0 = js * 19;
  const int NC = 3 * wid;

  const int wave = tid >> 6, lane = tid & 63;
  const int lo = lane & 15, hi = lane >> 4;

  using frag = __attribute__((ext_vector_type(8))) short;
  using f32x4v = __attribute__((ext_vector_type(4))) float;

  frag wfr[3][10];
  {
    const int row = wave * 16 + lo;
#pragma unroll
    for (int s = 0; s < 3; ++s)
#pragma unroll
      for (int kf = 0; kf < 10; ++kf)
        wfr[s][kf] = *(const frag*)(Wb3 + ((long)(js * 3 + s) * 64 + row) * 320
                                         + kf * 32 + hi * 8);
  }

  const bool gact = tid < 8 * wid;
  const int grow = gact ? (tid / wid) : 0;
  const int gcol = gact ? (tid - grow * wid) : 0;
  const int gjj = jj0 + gcol;
  float bhr = 0.f, bhz = 0.f, bhn = 0.f;
  if (gact){ bhr = bhh[gjj]; bhz = bhh[DD + gjj]; bhn = bhh[2*DD + gjj]; }

  for (int i = tid; i < 8 * S1PAD; i += 256) ((float*)hs)[i] = 0.f;
  for (int i = tid; i < 3840; i += 256) ((unsigned int*)hb)[i] = 0u;
  __syncthreads();

  unsigned int* myflag = flagsA + bid * 16;

  for (int t = 0; t < TT; ++t){
    float gir = 0.f, giz = 0.f, gin = 0.f;
    if (gact){
      const float* gp = gi_all + ((long)t * BB + b0 + grow) * GG;
      gir = gp[gjj]; giz = gp[DD + gjj]; gin = gp[2*DD + gjj];
    }

    f32x4v a0 = {0,0,0,0}, a1 = {0,0,0,0}, a2 = {0,0,0,0};
#pragma unroll
    for (int kf = 0; kf < 10; ++kf){
      frag h1 = *(const frag*)&hb[0][lo & 7][kf * 32 + hi * 8];
      frag h2 = *(const frag*)&hb[1][lo & 7][kf * 32 + hi * 8];
      frag h3 = *(const frag*)&hb[2][lo & 7][kf * 32 + hi * 8];
      a0 = __builtin_amdgcn_mfma_f32_16x16x32_bf16(h1, wfr[0][kf], a0, 0, 0, 0);
      a1 = __builtin_amdgcn_mfma_f32_16x16x32_bf16(h1, wfr[1][kf], a1, 0, 0, 0);
      a2 = __builtin_amdgcn_mfma_f32_16x16x32_bf16(h1, wfr[2][kf], a2, 0, 0, 0);
      a0 = __builtin_amdgcn_mfma_f32_16x16x32_bf16(h2, wfr[0][kf], a0, 0, 0, 0);
      a1 = __builtin_amdgcn_mfma_f32_16x16x32_bf16(h2, wfr[1][kf], a1, 0, 0, 0);
      a2 = __builtin_amdgcn_mfma_f32_16x16x32_bf16(h2, wfr[2][kf], a2, 0, 0, 0);
      a0 = __builtin_amdgcn_mfma_f32_16x16x32_bf16(h3, wfr[0][kf], a0, 0, 0, 0);
      a1 = __builtin_amdgcn_mfma_f32_16x16x32_bf16(h3, wfr[1][kf], a1, 0, 0, 0);
      a2 = __builtin_amdgcn_mfma_f32_16x16x32_bf16(h3, wfr[2][kf], a2, 0, 0, 0);
    }
    {
      const int nc = wave * 16 + lo;
      if (hi < 2 && nc < NC){
#pragma unroll
        for (int j = 0; j < 4; ++j)
          ghs[nc * 8 + hi * 4 + j] = (a0[j] + a1[j]) + a2[j];
      }
    }
    __syncthreads();

    const int par = t & 1;
    if (gact){
      const float r = jsigmoid(gir + ghs[(0 * wid + gcol) * 8 + grow] + bhr);
      const float z = jsigmoid(giz + ghs[(1 * wid + gcol) * 8 + grow] + bhz);
      const float n = tanhf(gin + r * (ghs[(2 * wid + gcol) * 8 + grow] + bhn));
      const float hn = (1.0f - z) * n + z * hs[grow][gjj];
      hx_all[((long)t * BB + b0 + grow) * DD + gjj] = hn;
      if (t < TT - 1)
        store_u32_llc(hex + ((long)par * BB + b0 + grow) * S1PAD + gjj,
                      __float_as_uint(hn));
    }

    if (t < TT - 1){
      asm volatile("s_waitcnt vmcnt(0)" ::: "memory");
      __syncthreads();
      if (tid == 0) store_u32_llc(myflag, (unsigned)(t + 1));
      if (tid < 16){
        const unsigned int* fp = flagsA + (bq * 16 + tid) * 16;
        unsigned v = poll_u32_llc(fp);
        while (v < (unsigned)(t + 1)){
          __builtin_amdgcn_s_sleep(1);
          v = poll_u32_llc(fp);
        }
      }
      __syncthreads();
      {
        const float* src = hex + (long)par * BB * S1PAD + (long)b0 * S1PAD;
        const int gA = tid, gB = tid + 256, gC = tid + 512;
        const int rA = gA / 76, cA = gA - rA * 76;
        const int rB = gB / 76, cB = gB - rB * 76;
        int rC = 0, cC = 0;
        u32x4 vA = load_b128_llc(src + (long)rA * S1PAD + cA * 4);
        u32x4 vB = load_b128_llc(src + (long)rB * S1PAD + cB * 4);
        u32x4 vC = (u32x4){0,0,0,0};
        if (gC < 608){
          rC = gC / 76; cC = gC - rC * 76;
          vC = load_b128_llc(src + (long)rC * S1PAD + cC * 4);
        }
        WAITV(0);
#define CONV_STORE(rr, cc, vv) do{ \
        float f0 = __uint_as_float(vv[0]), f1 = __uint_as_float(vv[1]); \
        float f2v = __uint_as_float(vv[2]), f3 = __uint_as_float(vv[3]); \
        if ((cc) == 75){ f0 = 0.f; f1 = 0.f; f2v = 0.f; f3 = 0.f; } \
        *(u32x4*)&hs[rr][(cc) * 4] = vv; \
        float fv[4] = {f0, f1, f2v, f3}; \
        unsigned short s1[4], s2[4], s3[4]; \
        _Pragma("unroll") \
        for (int j = 0; j < 4; ++j){ \
          s1[j] = f2bf(fv[j]); \
          const float r1 = fv[j] - bf2f(s1[j]); \
          s2[j] = f2bf(r1); \
          s3[j] = f2bf(r1 - bf2f(s2[j])); \
        } \
        *(uint2*)&hb[0][rr][(cc) * 4] = *(const uint2*)s1; \
        *(uint2*)&hb[1][rr][(cc) * 4] = *(const uint2*)s2; \
        *(uint2*)&hb[2][rr][(cc) * 4] = *(const uint2*)s3; \
      }while(0)
        CONV_STORE(rA, cA, vA);
        CONV_STORE(rB, cB, vB);
        if (gC < 608) CONV_STORE(rC, cC, vC);
#undef CONV_STORE
      }
      __syncthreads();
    }
  }
}

// ---------------- sampling (texts written in MFMA-fragment order) ------------
__global__ __launch_bounds__(256) void k_sample(
    const float* __restrict__ X, const float* __restrict__ mu_all,
    unsigned short* __restrict__ tF, float* __restrict__ out,
    const uint32_t k0a, const uint32_t k0b, const uint32_t k1a, const uint32_t k1b,
    const uint32_t k2a, const uint32_t k2b, const uint32_t k3a, const uint32_t k3b)
{
  const int r = blockIdx.x;            // t*128 + b
  const int t = r >> 7, b = r & 127;
  const int tid = threadIdx.x;
  const int h = tid >> 7, lane = tid & 127;
  const int wv = tid >> 6;
  __shared__ float redw[4];
  __shared__ int   redi4[4];
  __shared__ float yw[2], lyw[2], att_s[2];

  const uint32_t rowbase = (uint32_t)((t * 256 + b * 2 + h) * 500);
  float zv[4], ev[4];
  float lmax = -3.0e38f;
#pragma unroll
  for (int s = 0; s < 4; ++s){
    const int a = lane + s * 128;
    float z = -3.0e38f;
    if (a < ASP){
      float g = jgumbel(k0a, k0b, rowbase + (uint32_t)a);
      float m = mu_all[(long)r * NMU + h * ASP + a];
      z = (m + g) / 0.8f;
    }
    zv[s] = z;
    lmax = fmaxf(lmax, z);
  }
  {
    float wm = lmax;
#pragma unroll
    for (int o = 32; o > 0; o >>= 1) wm = fmaxf(wm, __shfl_xor(wm, o));
    if ((tid & 63) == 0) redw[wv] = wm;
  }
  __syncthreads();
  const float mx = fmaxf(redw[h * 2], redw[h * 2 + 1]);
  __syncthreads();

  float lsum = 0.0f;
#pragma unroll
  for (int s = 0; s < 4; ++s){
    const int a = lane + s * 128;
    float e = 0.0f;
    if (a < ASP) e = expf(zv[s] - mx);
    ev[s] = e;
    lsum += e;
  }
  {
    float wsum = lsum;
#pragma unroll
    for (int o = 32; o > 0; o >>= 1) wsum += __shfl_xor(wsum, o);
    if ((tid & 63) == 0) redw[wv] = wsum;
  }
  __syncthreads();
  const float S = redw[h * 2] + redw[h * 2 + 1];
  __syncthreads();

  float bestv = -3.0e38f;
  int besti = 0x7fffffff;
#pragma unroll
  for (int s = 0; s < 4; ++s){
    const int a = lane + s * 128;
    if (a < ASP){
      float y = ev[s] / S;
      float ly = logf(y);
      float gc = jgumbel(k1a, k1b, rowbase + (uint32_t)a);
      float val = ly + gc;
      if (val > bestv){ bestv = val; besti = a; }
    }
  }
  {
    float bv = bestv; int bi = besti;
#pragma unroll
    for (int o = 32; o > 0; o >>= 1){
      float v2 = __shfl_xor(bv, o);
      int   i2 = __shfl_xor(bi, o);
      if (v2 > bv || (v2 == bv && i2 < bi)){ bv = v2; bi = i2; }
    }
    if ((tid & 63) == 0){ redw[wv] = bv; redi4[wv] = bi; }
  }
  __syncthreads();
  int ind;
  {
    const float v0 = redw[h * 2], v1 = redw[h * 2 + 1];
    const int   i0 = redi4[h * 2], i1 = redi4[h * 2 + 1];
    ind = (v1 > v0 || (v1 == v0 && i1 < i0)) ? i1 : i0;
  }
#pragma unroll
  for (int s = 0; s < 4; ++s){
    const int a = lane + s * 128;
    if (a == ind){
      float y = ev[s] / S;
      yw[h] = y;
      lyw[h] = logf(y);
    }
  }
  __syncthreads();
  if (lane == 0){
    const float yv = yw[h];
    const float ly = lyw[h];
    const float yh = (1.0f - yv) + yv;
    const float act = ((float)ind * yh) / 500.0f;
    const float lvr = mu_all[(long)r * NMU + 1000 + h];
    const float lv = fmaxf(lvr, 0.0f) + log1pf(expf(-fabsf(lvr)));
    const float sd = expf(0.5f * lv);
    const uint32_t ei = (uint32_t)(r * 2 + h);
    const float e1 = jnormal(k2a, k2b, ei);
    const float e2 = jnormal(k3a, k3b, ei);
    const float s1 = act + sd * e1;
    const float s2 = act + sd * e2;
    const float dd = (s2 - act) / sd;
    const float lp = -0.5f * (dd * dd) - logf(sd) - 0.9189385332046727f;
    const float attv = 20.0f * jsigmoid(s1);
    out[OUT_SLOG + (long)b * 256 + t * 2 + h]  = ly;
    out[OUT_ACT  + (long)b * 256 + h * 128 + t] = act;
    out[OUT_LOGP + (long)b * 256 + h * 128 + t] = lp;
    att_s[h] = attv;
  }
  __syncthreads();
  const float* xr = X + ((long)b * TT + t) * DD;
  if (tid < 40){
    unsigned short pk[8];
#pragma unroll
    for (int e = 0; e < 8; ++e){
      const int idx = tid * 8 + e;
      float v = 0.0f;
      if (idx < 300) v = xr[idx] * att_s[idx / 150];
      pk[e] = f2bf(v);
    }
    unsigned short* dst = tF + (((long)t * 8 + (b >> 4)) * 40 + tid) * 128
                             + (b & 15) * 8;
    *(uint4*)dst = *(const uint4*)pk;
  }
}

// ---------------- weight conversion to bf16 (stage-2) ----------------
__global__ __launch_bounds__(256) void k_cvt_whh(
    const float* __restrict__ W, unsigned short* __restrict__ O)
{
  const int i = blockIdx.x * 256 + threadIdx.x;   // 3072*1024
  O[i] = f2bf(W[i]);
}

__global__ __launch_bounds__(256) void k_cvt_wih(
    const float* __restrict__ W, unsigned short* __restrict__ O)
{
  const int i = blockIdx.x * 256 + threadIdx.x;   // 3072*320
  const int rw = i / 320, c = i - rw * 320;
  O[i] = (c < DD) ? f2bf(W[(long)rw * DD + c]) : (unsigned short)0;
}

// ---------------- stage-2 persistent: 128 blocks x 512 thr ----------------
// Waves = (mt in {0,1} M-half) x (kg in {0..3} K-group). HIDDEN W fragments
// REGISTER-resident (24 frags/wave, loaded once) -> zero LDS reads in the
// hidden phase (R17 was LDS-issue-bound: ~528 ds_read_b128/step). Texts W in
// padded LDS (pitch 328). Cross-kg partial reduce via LDS; epilogue by kg=0
// waves. A-frags direct-from-global (frag-ordered), counted-vmcnt ladders.
#define NBLK2 128
#define PBASE 31488
#define TLBASE 80640

__global__ __launch_bounds__(512) void k_stage2(
    const unsigned short* __restrict__ tF,
    const unsigned short* __restrict__ Whb,
    const unsigned short* __restrict__ Wib,
    const float* __restrict__ bih, const float* __restrict__ bhh,
    const int* __restrict__ lengths,
    unsigned short* __restrict__ hF0, unsigned short* __restrict__ hF1,
    float* __restrict__ last,
    unsigned int* __restrict__ flags)
{
  __shared__ __align__(16) char lds[82688];  // WlT 31488 | P 49152 | Tl 2048
  unsigned short* WlT = (unsigned short*)lds;            // [48][328]
  char* Pb = lds + PBASE;
  unsigned short* Tl = (unsigned short*)(lds + TLBASE);

  const int tid = threadIdx.x;
  const int bid = blockIdx.x;
  const int m = bid >> 6, n = bid & 63;
  const int e0 = n * 16, mrow = m * 64;
  const int wave = tid >> 6, mt = wave >> 2, kg = wave & 3;
  const int lane = tid & 63, lo = lane & 15, hi = lane >> 4;

  using frag = __attribute__((ext_vector_type(8))) short;
  using f32x4 = __attribute__((ext_vector_type(4))) float;

  // stage texts W (48 x 320 bf16, pitch 328) into LDS
  for (int s = tid; s < 48 * 40; s += 512){
    const int row = s / 40, q = s - row * 40;
    const int g = row >> 4, nn = row & 15;
    *(uint4*)((char*)WlT + row * 656 + q * 16) =
        *(const uint4*)(Wib + (long)(g * EE + e0 + nn) * 320 + q * 8);
  }

  // preload hidden W-frags into registers: 4 chunks x 3 gates x 2 kf
  frag wfrH[4][3][2];
#pragma unroll
  for (int i = 0; i < 4; ++i)
#pragma unroll
    for (int g = 0; g < 3; ++g)
#pragma unroll
      for (int kf = 0; kf < 2; ++kf)
        wfrH[i][g][kf] = *(const frag*)(Whb + ((long)g * EE + e0 + lo) * EE
                                        + (kg * 4 + i) * 64 + kf * 32 + hi * 8);

  const int e = e0 + lo;
  const float bR = bih[e] + bhh[e];
  const float bZ = bih[EE + e] + bhh[EE + e];
  const float biN = bih[2*EE + e];
  const float bhN = bhh[2*EE + e];
  int li[2][4]; float hp[2][4];
#pragma unroll
  for (int sub = 0; sub < 2; ++sub)
#pragma unroll
    for (int j = 0; j < 4; ++j){
      const int brow = (mt * 2 + sub) * 16 + hi * 4 + j;
      int l = lengths[mrow + brow] - 1; if (l < 0) l += TT;
      li[sub][j] = l; hp[sub][j] = 0.0f;
    }
  __syncthreads();

  const int rg0 = m * 4 + mt * 2, rg1 = rg0 + 1;
  const long hOff0 = (long)rg0 * 16384 + hi * 128 + lo * 8;
  const long hOff1 = (long)rg1 * 16384 + hi * 128 + lo * 8;
  const long tOff0 = (long)rg0 * 5120 + hi * 128 + lo * 8;
  const long tOff1 = (long)rg1 * 5120 + hi * 128 + lo * 8;

  unsigned int* flagp = flags + (m << 6) + n;

#define TEXB(g, kf, cp) (*(const frag*)((char*)WlT + ((g)*16 + lo)*656 \
                          + ((cp)*64 + (kf)*32 + hi*8)*2))

  for (int t = 0; t < TT; ++t){
    const unsigned short* hFin = (t & 1) ? hF1 : hF0;
    unsigned short* hFout = (t & 1) ? hF0 : hF1;
    const unsigned short* tB = tF + (long)t * 5120 * 8;

    f32x4 accR[2], accZ[2], accNH[2], accNI[2];
#pragma unroll
    for (int s = 0; s < 2; ++s){
      accR[s] = (f32x4){0,0,0,0}; accZ[s] = (f32x4){0,0,0,0};
      accNH[s] = (f32x4){0,0,0,0}; accNI[s] = (f32x4){0,0,0,0};
    }

    auto mfm6 = [&](frag a0k0, frag a0k1, frag a1k0, frag a1k1,
                    frag b00, frag b01, frag b10, frag b11,
                    frag b20, frag b21, bool hid){
      accR[0] = __builtin_amdgcn_mfma_f32_16x16x32_bf16(a0k0, b00, accR[0], 0, 0, 0);
      accR[0] = __builtin_amdgcn_mfma_f32_16x16x32_bf16(a0k1, b01, accR[0], 0, 0, 0);
      accR[1] = __builtin_amdgcn_mfma_f32_16x16x32_bf16(a1k0, b00, accR[1], 0, 0, 0);
      accR[1] = __builtin_amdgcn_mfma_f32_16x16x32_bf16(a1k1, b01, accR[1], 0, 0, 0);
      accZ[0] = __builtin_amdgcn_mfma_f32_16x16x32_bf16(a0k0, b10, accZ[0], 0, 0, 0);
      accZ[0] = __builtin_amdgcn_mfma_f32_16x16x32_bf16(a0k1, b11, accZ[0], 0, 0, 0);
      accZ[1] = __builtin_amdgcn_mfma_f32_16x16x32_bf16(a1k0, b10, accZ[1], 0, 0, 0);
      accZ[1] = __builtin_amdgcn_mfma_f32_16x16x32_bf16(a1k1, b11, accZ[1], 0, 0, 0);
      if (hid){
        accNH[0] = __builtin_amdgcn_mfma_f32_16x16x32_bf16(a0k0, b20, accNH[0], 0, 0, 0);
        accNH[0] = __builtin_amdgcn_mfma_f32_16x16x32_bf16(a0k1, b21, accNH[0], 0, 0, 0);
        accNH[1] = __builtin_amdgcn_mfma_f32_16x16x32_bf16(a1k0, b20, accNH[1], 0, 0, 0);
        accNH[1] = __builtin_amdgcn_mfma_f32_16x16x32_bf16(a1k1, b21, accNH[1], 0, 0, 0);
      } else {
        accNI[0] = __builtin_amdgcn_mfma_f32_16x16x32_bf16(a0k0, b20, accNI[0], 0, 0, 0);
        accNI[0] = __builtin_amdgcn_mfma_f32_16x16x32_bf16(a0k1, b21, accNI[0], 0, 0, 0);
        accNI[1] = __builtin_amdgcn_mfma_f32_16x16x32_bf16(a1k0, b20, accNI[1], 0, 0, 0);
        accNI[1] = __builtin_amdgcn_mfma_f32_16x16x32_bf16(a1k1, b21, accNI[1], 0, 0, 0);
      }
    };

    // ---- texts phase (skew absorber; before poll) ----
    if (kg == 0){
      u32x4 a00 = load_b128_llc(tB + tOff0);
      u32x4 a01 = load_b128_llc(tB + tOff0 + 512);
      u32x4 a10 = load_b128_llc(tB + tOff1);
      u32x4 a11 = load_b128_llc(tB + tOff1 + 512);
      u32x4 b00 = load_b128_llc(tB + tOff0 + 1024);
      u32x4 b01 = load_b128_llc(tB + tOff0 + 1536);
      u32x4 b10 = load_b128_llc(tB + tOff1 + 1024);
      u32x4 b11 = load_b128_llc(tB + tOff1 + 1536);
      WAITV(4);
      mfm6(*(frag*)&a00, *(frag*)&a01, *(frag*)&a10, *(frag*)&a11,
           TEXB(0,0,0), TEXB(0,1,0), TEXB(1,0,0), TEXB(1,1,0),
           TEXB(2,0,0), TEXB(2,1,0), false);
      WAITV(0);
      mfm6(*(frag*)&b00, *(frag*)&b01, *(frag*)&b10, *(frag*)&b11,
           TEXB(0,0,1), TEXB(0,1,1), TEXB(1,0,1), TEXB(1,1,1),
           TEXB(2,0,1), TEXB(2,1,1), false);
    } else {
      const int cp = kg + 1;   // 2,3,4
      u32x4 a00 = load_b128_llc(tB + tOff0 + cp * 1024);
      u32x4 a01 = load_b128_llc(tB + tOff0 + cp * 1024 + 512);
      u32x4 a10 = load_b128_llc(tB + tOff1 + cp * 1024);
      u32x4 a11 = load_b128_llc(tB + tOff1 + cp * 1024 + 512);
      WAITV(0);
      mfm6(*(frag*)&a00, *(frag*)&a01, *(frag*)&a10, *(frag*)&a11,
           TEXB(0,0,cp), TEXB(0,1,cp), TEXB(1,0,cp), TEXB(1,1,cp),
           TEXB(2,0,cp), TEXB(2,1,cp), false);
    }

    // ---- poll + hidden phase (4 chunks, register B) ----
    if (t > 0){
      if (tid < 16){
        const unsigned int* fp = flags + (m << 6) + tid * 4;
        for (;;){
          u32x4 f = load_b128_llc(fp);
          WAITV(0);
          if (f[0] >= (unsigned)t && f[1] >= (unsigned)t &&
              f[2] >= (unsigned)t && f[3] >= (unsigned)t) break;
          __builtin_amdgcn_s_sleep(2);
        }
      }
      __syncthreads();

      u32x4 ha[4][2][2];
#pragma unroll
      for (int i = 0; i < 4; ++i){
        const long co = (long)(kg * 4 + i) * 1024;
        ha[i][0][0] = load_b128_llc(hFin + hOff0 + co);
        ha[i][0][1] = load_b128_llc(hFin + hOff0 + co + 512);
        ha[i][1][0] = load_b128_llc(hFin + hOff1 + co);
        ha[i][1][1] = load_b128_llc(hFin + hOff1 + co + 512);
      }
      WAITV(12);
      mfm6(*(frag*)&ha[0][0][0], *(frag*)&ha[0][0][1],
           *(frag*)&ha[0][1][0], *(frag*)&ha[0][1][1],
           wfrH[0][0][0], wfrH[0][0][1], wfrH[0][1][0], wfrH[0][1][1],
           wfrH[0][2][0], wfrH[0][2][1], true);
      WAITV(8);
      mfm6(*(frag*)&ha[1][0][0], *(frag*)&ha[1][0][1],
           *(frag*)&ha[1][1][0], *(frag*)&ha[1][1][1],
           wfrH[1][0][0], wfrH[1][0][1], wfrH[1][1][0], wfrH[1][1][1],
           wfrH[1][2][0], wfrH[1][2][1], true);
      WAITV(4);
      mfm6(*(frag*)&ha[2][0][0], *(frag*)&ha[2][0][1],
           *(frag*)&ha[2][1][0], *(frag*)&ha[2][1][1],
           wfrH[2][0][0], wfrH[2][0][1], wfrH[2][1][0], wfrH[2][1][1],
           wfrH[2][2][0], wfrH[2][2][1], true);
      WAITV(0);
      mfm6(*(frag*)&ha[3][0][0], *(frag*)&ha[3][0][1],
           *(frag*)&ha[3][1][0], *(frag*)&ha[3][1][1],
           wfrH[3][0][0], wfrH[3][0][1], wfrH[3][1][0], wfrH[3][1][1],
           wfrH[3][2][0], wfrH[3][2][1], true);
    }

    // ---- cross-kg partial reduce ----
    if (kg != 0){
      char* dst = Pb + ((kg - 1) * 2 + mt) * 8192;
#pragma unroll
      for (int sub = 0; sub < 2; ++sub){
        *(f32x4*)(dst + ((sub * 4 + 0) * 64 + lane) * 16) = accR[sub];
        *(f32x4*)(dst + ((sub * 4 + 1) * 64 + lane) * 16) = accZ[sub];
        *(f32x4*)(dst + ((sub * 4 + 2) * 64 + lane) * 16) = accNH[sub];
        *(f32x4*)(dst + ((sub * 4 + 3) * 64 + lane) * 16) = accNI[sub];
      }
    }
    __syncthreads();
    if (kg == 0){
#pragma unroll
      for (int p = 0; p < 3; ++p){
        const char* src = Pb + (p * 2 + mt) * 8192;
#pragma unroll
        for (int sub = 0; sub < 2; ++sub){
          const f32x4 pR  = *(const f32x4*)(src + ((sub*4 + 0) * 64 + lane) * 16);
          const f32x4 pZ  = *(const f32x4*)(src + ((sub*4 + 1) * 64 + lane) * 16);
          const f32x4 pNH = *(const f32x4*)(src + ((sub*4 + 2) * 64 + lane) * 16);
          const f32x4 pNI = *(const f32x4*)(src + ((sub*4 + 3) * 64 + lane) * 16);
#pragma unroll
          for (int j = 0; j < 4; ++j){
            accR[sub][j] += pR[j]; accZ[sub][j] += pZ[j];
            accNH[sub][j] += pNH[j]; accNI[sub][j] += pNI[j];
          }
        }
      }
      // GRU gates epilogue
#pragma unroll
      for (int sub = 0; sub < 2; ++sub)
#pragma unroll
        for (int j = 0; j < 4; ++j){
          const int brow = (mt * 2 + sub) * 16 + hi * 4 + j;
          const float r = jsigmoid(accR[sub][j] + bR);
          const float z = jsigmoid(accZ[sub][j] + bZ);
          const float nn2 = tanhf(accNI[sub][j] + biN + r * (accNH[sub][j] + bhN));
          const float hn = (1.0f - z) * nn2 + z * hp[sub][j];
          hp[sub][j] = hn;
          Tl[brow * 16 + lo] = f2bf(hn);
          if (t == li[sub][j]) last[(long)(mrow + brow) * EE + e] = hn;
        }
    }

    if (t < TT - 1){
      __syncthreads();                 // Tl visible to all
      if (tid < 128){
        const int rgp = tid >> 5;
        const int kbp = (tid >> 4) & 1;
        const int lop = tid & 15;
        u32x4 v = *(const u32x4*)(Tl + (rgp * 16 + lop) * 16 + kbp * 8);
        store_b128_llc(hFout + ((long)(m * 4 + rgp) * 128 + (n * 2 + kbp)) * 128
                             + lop * 8, v);
      }
      asm volatile("s_waitcnt vmcnt(0)" ::: "memory");
      __syncthreads();
      if (tid == 0) store_u32_llc(flagp, (unsigned)(t + 1));
    }
  }
#undef TEXB
}

// ---------------- BatchNorm ----------------
__global__ __launch_bounds__(256) void k_bn_stats(
    const float* __restrict__ last, float* __restrict__ mv)
{
  const int e = blockIdx.x * 256 + threadIdx.x;
  if (e >= EE) return;
  float s = 0.0f;
  for (int b = 0; b < BB; ++b) s += last[(long)b * EE + e];
  const float mean = s / 128.0f;
  float v = 0.0f;
  for (int b = 0; b < BB; ++b){ float d = last[(long)b * EE + e] - mean; v += d * d; }
  mv[e] = mean;
  mv[EE + e] = v / 128.0f;
}

__global__ __launch_bounds__(256) void k_bn_apply(
    const float* __restrict__ last, const float* __restrict__ mv,
    const float* __restrict__ gamma, const float* __restrict__ beta,
    float* __restrict__ out)
{
  const int gid = blockIdx.x * 256 + threadIdx.x;
  const int e = gid & 1023;
  const float xm = last[gid] - mv[e];
  out[gid] = gamma[e] * xm / sqrtf(mv[EE + e] + 1e-5f) + beta[e];
}

// ---------------- launcher ----------------
extern "C" void kernel_launch(void* const* d_in, const int* in_sizes, int n_in,
                              void* d_out, int out_size, void* d_ws, size_t ws_size,
                              hipStream_t stream)
{
  (void)in_sizes; (void)n_in; (void)out_size;
  const float* x     = (const float*)d_in[0];
  const int*   lens  = (const int*)d_in[1];
  const float* Wih_c = (const float*)d_in[3];
  const float* Whh_c = (const float*)d_in[4];
  const float* bih_c = (const float*)d_in[5];
  const float* bhh_c = (const float*)d_in[6];
  const float* Wmu   = (const float*)d_in[7];
  const float* bmu   = (const float*)d_in[8];
  const float* Wlv   = (const float*)d_in[9];
  const float* blv   = (const float*)d_in[10];
  const float* Wih_r = (const float*)d_in[11];
  const float* Whh_r = (const float*)d_in[12];
  const float* bih_r = (const float*)d_in[13];
  const float* bhh_r = (const float*)d_in[14];
  const float* gam   = (const float*)d_in[15];
  const float* bet   = (const float*)d_in[16];
  float* out = (float*)d_out;

  uint32_t nk[4][2];
  for (uint32_t i = 0; i < 4; ++i) tf2x32(0u, 42u, 0u, i, &nk[i][0], &nk[i][1]);

  float* ws = (float*)d_ws;
  size_t off = 0;
  float* U       = ws + off; off += 16515072;  // gi_all then mu_all[16384][1008]
  float* hx_all  = ws + off; off += 4915200;
  float* lastb   = ws + off; off += 131072;
  float* mv      = ws + off; off += 2048;
  float* hex     = ws + off; off += 77824;     // [2][128][304] f32 stage-1 exchange
  float* biasM   = ws + off; off += 1024;      // fused mu+lv bias
  unsigned int* flags  = (unsigned int*)(ws + off); off += 2048;  // stage-2 packed [m][64]
  unsigned int* flagsA = (unsigned int*)(ws + off); off += 4096;  // stage-1: 256*16
  unsigned short* tF  = (unsigned short*)(ws + off); off += 2621440; // texts frag order
  unsigned short* hF0 = (unsigned short*)(ws + off); off += 65536;
  unsigned short* hF1 = (unsigned short*)(ws + off); off += 65536;
  unsigned short* Whb = (unsigned short*)(ws + off); off += 1572864; // 3072x1024 bf16
  unsigned short* Wib = (unsigned short*)(ws + off); off += 491520;  // 3072x320 bf16
  unsigned short* Wb3 = (unsigned short*)(ws + off); off += 491520;  // [16][3][64][320] bf16
  unsigned short* WmH = (unsigned short*)(ws + off); off += 311296;  // 1024x608 bf16
  unsigned short* WmL = (unsigned short*)(ws + off); off += 311296;
  unsigned short* AmH = (unsigned short*)(ws + off); off += 4980736; // 16384x608 bf16
  unsigned short* AmL = (unsigned short*)(ws + off); off += 4980736;
  if (ws_size < off * sizeof(float)) return;

  hipMemsetAsync(flags, 0, 2048 * sizeof(unsigned int), stream);
  hipMemsetAsync(flagsA, 0, 4096 * sizeof(unsigned int), stream);

  // weight prep
  k_cvt_whh<<<dim3(12288), 256, 0, stream>>>(Whh_r, Whb);
  k_cvt_wih<<<dim3(3840), 256, 0, stream>>>(Wih_r, Wib);
  k_pack_w3<<<dim3(960), 256, 0, stream>>>(Whh_c, Wb3);
  k_cvt_Wmu<<<dim3(608), 256, 0, stream>>>(Wmu, Wlv, WmH, WmL);
  k_bias_mu<<<dim3(4), 256, 0, stream>>>(bmu, blv, biasM);

  // stage-1 input projection (fp32) + persistent MFMA recurrence
  k_gemm_gi<<<dim3(15, 128), 256, 0, stream>>>(x, Wih_c, bih_c, U);
  k_stage1<<<dim3(256), 256, 0, stream>>>(Wb3, bhh_c, U, hx_all, hex, flagsA);

  // mu+lv via split-bf16 4-term MFMA, then sampling
  k_cvt_Amu<<<dim3(9728), 256, 0, stream>>>(x, hx_all, AmH, AmL);
  k_gemm_mf<<<dim3(16, 128), 256, 0, stream>>>(AmH, AmL, WmH, WmL, biasM, U);
  k_sample<<<dim3(16384), 256, 0, stream>>>(x, U, tF, out,
      nk[0][0], nk[0][1], nk[1][0], nk[1][1],
      nk[2][0], nk[2][1], nk[3][0], nk[3][1]);

  // stage-2 persistent recurrence (register-B hidden, 4-way K-split)
  k_stage2<<<dim3(NBLK2), 512, 0, stream>>>(tF, Whb, Wib, bih_r, bhh_r, lens,
                                            hF0, hF1, lastb, flags);

  // batchnorm
  k_bn_stats<<<dim3(4), 256, 0, stream>>>(lastb, mv);
  k_bn_apply<<<dim3(512), 256, 0, stream>>>(lastb, mv, gam, bet, out);
}

// Round 19
// 1419.393 us; speedup vs baseline: 1.4077x; 1.4077x over previous
//
#include <hip/hip_runtime.h>
#include <stdint.h>

#define TT 128
#define BB 128
#define DD 300
#define EE 1024
#define GG 900
#define NMU 1008
#define ASP 500
#define KP 608

#define OUT_SLOG 131072
#define OUT_ACT  163840
#define OUT_LOGP 196608

typedef unsigned int u32x4 __attribute__((ext_vector_type(4)));

// ---------------- threefry2x32 (JAX, 20 rounds) ----------------
__host__ __device__ static inline uint32_t rotl32(uint32_t x, int r){
  return (x << r) | (x >> (32 - r));
}

__host__ __device__ static inline void tf2x32(uint32_t k0, uint32_t k1,
                                              uint32_t x0, uint32_t x1,
                                              uint32_t* o0, uint32_t* o1){
  uint32_t ks2 = k0 ^ k1 ^ 0x1BD11BDAu;
#define TFR(r) { x0 += x1; x1 = rotl32(x1, r); x1 ^= x0; }
  x0 += k0; x1 += k1;
  TFR(13) TFR(15) TFR(26) TFR(6)
  x0 += k1; x1 += ks2 + 1u;
  TFR(17) TFR(29) TFR(16) TFR(24)
  x0 += ks2; x1 += k0 + 2u;
  TFR(13) TFR(15) TFR(26) TFR(6)
  x0 += k0; x1 += k1 + 3u;
  TFR(17) TFR(29) TFR(16) TFR(24)
  x0 += k1; x1 += ks2 + 4u;
  TFR(13) TFR(15) TFR(26) TFR(6)
  x0 += ks2; x1 += k0 + 5u;
#undef TFR
  *o0 = x0; *o1 = x1;
}

__device__ static inline uint32_t rng32(uint32_t k0, uint32_t k1, uint32_t idx){
  uint32_t a, b;
  tf2x32(k0, k1, 0u, idx, &a, &b);
  return a ^ b;
}

__device__ static inline float u01(uint32_t bits){
  return __uint_as_float((bits >> 9) | 0x3f800000u) - 1.0f;
}

__device__ static inline float jgumbel(uint32_t k0, uint32_t k1, uint32_t idx){
  float u = u01(rng32(k0, k1, idx));
  float l1 = logf(u + 1e-20f);
  return -logf(-l1 + 1e-20f);
}

__device__ static inline float erfinv32(float x){   // XLA ErfInv32 (Giles)
  float w = -log1pf(-x * x);
  float p;
  if (w < 5.0f){
    w = w - 2.5f;
    p = 2.81022636e-08f;
    p = 3.43273939e-07f  + p * w;
    p = -3.5233877e-06f  + p * w;
    p = -4.39150654e-06f + p * w;
    p = 0.00021858087f   + p * w;
    p = -0.00125372503f  + p * w;
    p = -0.00417768164f  + p * w;
    p = 0.246640727f     + p * w;
    p = 1.50140941f      + p * w;
  } else {
    w = sqrtf(w) - 3.0f;
    p = -0.000200214257f;
    p = 0.000100950558f  + p * w;
    p = 0.00134934322f   + p * w;
    p = -0.00367342844f  + p * w;
    p = 0.00573950773f   + p * w;
    p = -0.0076224613f   + p * w;
    p = 0.00943887047f   + p * w;
    p = 1.00167406f      + p * w;
    p = 2.83297682f      + p * w;
  }
  return p * x;
}

__device__ static inline float jnormal(uint32_t k0, uint32_t k1, uint32_t idx){
  float u = u01(rng32(k0, k1, idx));
  const float lo = -0.99999994f;
  float v = u * 2.0f + lo;
  v = fmaxf(lo, v);
  return 1.41421356237f * erfinv32(v);
}

__device__ static inline float jsigmoid(float x){
  return 1.0f / (1.0f + expf(-x));
}

__device__ static inline unsigned short f2bf(float f){   // RNE f32->bf16
  uint32_t u = __float_as_uint(f);
  uint32_t r = (u + 0x7fffu + ((u >> 16) & 1u)) >> 16;
  return (unsigned short)r;
}
__device__ static inline float bf2f(unsigned short h){
  return __uint_as_float((uint32_t)h << 16);
}

// ---- LLC-coherent (cross-XCD) memory ops: sc0 sc1 = bypass L1+L2 ----
__device__ static inline u32x4 load_b128_llc(const void* p){
  u32x4 r;
  asm volatile("global_load_dwordx4 %0, %1, off sc0 sc1"
               : "=v"(r) : "v"(p) : "memory");
  return r;
}
__device__ static inline void store_b128_llc(void* p, u32x4 v){
  asm volatile("global_store_dwordx4 %0, %1, off sc0 sc1"
               :: "v"(p), "v"(v) : "memory");
}
__device__ static inline unsigned poll_u32_llc(const void* p){
  unsigned r;
  asm volatile("global_load_dword %0, %1, off sc0 sc1\n\ts_waitcnt vmcnt(0)"
               : "=v"(r) : "v"(p) : "memory");
  return r;
}
__device__ static inline void store_u32_llc(void* p, unsigned v){
  asm volatile("global_store_dword %0, %1, off sc0 sc1"
               :: "v"(p), "v"(v) : "memory");
}

#define WAITV(N) do{ asm volatile("s_waitcnt vmcnt(" #N ")" ::: "memory"); \
                     __builtin_amdgcn_sched_barrier(0); }while(0)

// ---------------- gi split-bf16 conversions ----------------
// AgX[r=(t*128+b)][320] = x[b][t] (NO relu), hi/lo bf16; k>=300 zero
__global__ __launch_bounds__(256) void k_cvt_Ax(
    const float* __restrict__ X,
    unsigned short* __restrict__ Ah, unsigned short* __restrict__ Al)
{
  const long i = (long)blockIdx.x * 256 + threadIdx.x;   // 16384*80
  const int r = (int)(i / 80), g = (int)(i - (long)r * 80);
  const int k = g * 4;
  const int b = r & 127, t = r >> 7;
  float4 v = {0,0,0,0};
  if (k < 300) v = *(const float4*)(X + ((long)b * TT + t) * DD + k);
  float vv[4] = {v.x, v.y, v.z, v.w};
  unsigned short hi[4], lo[4];
#pragma unroll
  for (int j = 0; j < 4; ++j){
    hi[j] = f2bf(vv[j]);
    lo[j] = f2bf(vv[j] - bf2f(hi[j]));
  }
  const long off = (long)r * 320 + k;
  *(uint2*)(Ah + off) = *(const uint2*)hi;
  *(uint2*)(Al + off) = *(const uint2*)lo;
}

// Wg[960][320] = [Wih_c(900x300); 0], hi/lo bf16
__global__ __launch_bounds__(256) void k_cvt_Wgi(
    const float* __restrict__ W,
    unsigned short* __restrict__ Wh, unsigned short* __restrict__ Wl)
{
  const int i = blockIdx.x * 256 + threadIdx.x;   // 960*80
  if (i >= 76800) return;
  const int r = i / 80, g = i - r * 80;
  const int k = g * 4;
  float4 v = {0,0,0,0};
  if (k < 300 && r < 900) v = *(const float4*)(W + (long)r * DD + k);
  float vv[4] = {v.x, v.y, v.z, v.w};
  unsigned short hi[4], lo[4];
#pragma unroll
  for (int j = 0; j < 4; ++j){
    hi[j] = f2bf(vv[j]);
    lo[j] = f2bf(vv[j] - bf2f(hi[j]));
  }
  const long off = (long)r * 320 + k;
  *(uint2*)(Wh + off) = *(const uint2*)hi;
  *(uint2*)(Wl + off) = *(const uint2*)lo;
}

// ---------------- gi GEMM: split-bf16 4-term MFMA, 128x64 tiles, K=320 -------
__global__ __launch_bounds__(256) void k_gemm_gf(
    const unsigned short* __restrict__ Ah, const unsigned short* __restrict__ Al,
    const unsigned short* __restrict__ Bh, const unsigned short* __restrict__ Bl,
    const float* __restrict__ bias, float* __restrict__ C)
{
  __shared__ __align__(16) unsigned short sAh[128][40], sAl[128][40];
  __shared__ __align__(16) unsigned short sBh[64][40], sBl[64][40];
  const int tid = threadIdx.x;
  const int cbase = blockIdx.x * 64, rbase = blockIdx.y * 128;
  const int wave = tid >> 6, wm = wave >> 1, wn = wave & 1;
  const int lane = tid & 63, lo = lane & 15, hi4 = lane >> 4;

  using frag = __attribute__((ext_vector_type(8))) short;
  using f32x4 = __attribute__((ext_vector_type(4))) float;
  f32x4 acc[4][2];
#pragma unroll
  for (int a = 0; a < 4; ++a)
#pragma unroll
    for (int c = 0; c < 2; ++c) acc[a][c] = (f32x4){0.f,0.f,0.f,0.f};

  const int arow = tid >> 1, akh = (tid & 1) * 16;
  const int brow = tid >> 2, bkh = (tid & 3) * 8;

  for (int kb = 0; kb < 10; ++kb){
    const int k0 = kb * 32;
    __syncthreads();
    {
      const unsigned short* pa = Ah + (long)(rbase + arow) * 320 + k0 + akh;
      *(uint4*)&sAh[arow][akh]     = *(const uint4*)pa;
      *(uint4*)&sAh[arow][akh + 8] = *(const uint4*)(pa + 8);
      const unsigned short* pl = Al + (long)(rbase + arow) * 320 + k0 + akh;
      *(uint4*)&sAl[arow][akh]     = *(const uint4*)pl;
      *(uint4*)&sAl[arow][akh + 8] = *(const uint4*)(pl + 8);
      *(uint4*)&sBh[brow][bkh] = *(const uint4*)(Bh + (long)(cbase + brow) * 320 + k0 + bkh);
      *(uint4*)&sBl[brow][bkh] = *(const uint4*)(Bl + (long)(cbase + brow) * 320 + k0 + bkh);
    }
    __syncthreads();
    frag bh0 = *(const frag*)&sBh[wn*32 + lo][hi4*8];
    frag bh1 = *(const frag*)&sBh[wn*32 + 16 + lo][hi4*8];
    frag bl0 = *(const frag*)&sBl[wn*32 + lo][hi4*8];
    frag bl1 = *(const frag*)&sBl[wn*32 + 16 + lo][hi4*8];
#pragma unroll
    for (int fr = 0; fr < 4; ++fr){
      frag ah = *(const frag*)&sAh[wm*64 + fr*16 + lo][hi4*8];
      frag al = *(const frag*)&sAl[wm*64 + fr*16 + lo][hi4*8];
      acc[fr][0] = __builtin_amdgcn_mfma_f32_16x16x32_bf16(ah, bh0, acc[fr][0], 0, 0, 0);
      acc[fr][0] = __builtin_amdgcn_mfma_f32_16x16x32_bf16(al, bh0, acc[fr][0], 0, 0, 0);
      acc[fr][0] = __builtin_amdgcn_mfma_f32_16x16x32_bf16(ah, bl0, acc[fr][0], 0, 0, 0);
      acc[fr][0] = __builtin_amdgcn_mfma_f32_16x16x32_bf16(al, bl0, acc[fr][0], 0, 0, 0);
      acc[fr][1] = __builtin_amdgcn_mfma_f32_16x16x32_bf16(ah, bh1, acc[fr][1], 0, 0, 0);
      acc[fr][1] = __builtin_amdgcn_mfma_f32_16x16x32_bf16(al, bh1, acc[fr][1], 0, 0, 0);
      acc[fr][1] = __builtin_amdgcn_mfma_f32_16x16x32_bf16(ah, bl1, acc[fr][1], 0, 0, 0);
      acc[fr][1] = __builtin_amdgcn_mfma_f32_16x16x32_bf16(al, bl1, acc[fr][1], 0, 0, 0);
    }
  }
#pragma unroll
  for (int fr = 0; fr < 4; ++fr)
#pragma unroll
    for (int fc = 0; fc < 2; ++fc){
      const int col = cbase + wn*32 + fc*16 + lo;
      if (col < GG){
        const float bv = bias[col];
        const int r0 = rbase + wm*64 + fr*16 + hi4*4;
#pragma unroll
        for (int j = 0; j < 4; ++j)
          C[(long)(r0 + j) * GG + col] = acc[fr][fc][j] + bv;
      }
    }
}

// ---------------- split-bf16 conversions for mu GEMM ----------------
__global__ __launch_bounds__(256) void k_cvt_Amu(
    const float* __restrict__ X, const float* __restrict__ HX,
    unsigned short* __restrict__ Ah, unsigned short* __restrict__ Al)
{
  const long i = (long)blockIdx.x * 256 + threadIdx.x;   // 16384*152 groups
  const int r = (int)(i / 152), g = (int)(i - (long)r * 152);
  const int k = g * 4;
  const int b = r & 127, t = r >> 7;
  float4 v = {0,0,0,0};
  if (k < 300)      v = *(const float4*)(X + ((long)b * TT + t) * DD + k);
  else if (k < 600) v = *(const float4*)(HX + (long)r * DD + (k - 300));
  float vv[4] = {fmaxf(v.x,0.f), fmaxf(v.y,0.f), fmaxf(v.z,0.f), fmaxf(v.w,0.f)};
  unsigned short hi[4], lo[4];
#pragma unroll
  for (int j = 0; j < 4; ++j){
    hi[j] = f2bf(vv[j]);
    lo[j] = f2bf(vv[j] - bf2f(hi[j]));
  }
  const long off = (long)r * KP + k;
  *(uint2*)(Ah + off) = *(const uint2*)hi;
  *(uint2*)(Al + off) = *(const uint2*)lo;
}

__global__ __launch_bounds__(256) void k_cvt_Wmu(
    const float* __restrict__ Wmu, const float* __restrict__ Wlv,
    unsigned short* __restrict__ Wh, unsigned short* __restrict__ Wl)
{
  const long i = (long)blockIdx.x * 256 + threadIdx.x;   // 1024*152 groups
  const int r = (int)(i / 152), g = (int)(i - (long)r * 152);
  const int k = g * 4;
  float4 v = {0,0,0,0};
  if (k < 600){
    if (r < 1000)      v = *(const float4*)(Wmu + (long)r * 600 + k);
    else if (r < 1002) v = *(const float4*)(Wlv + (long)(r - 1000) * 600 + k);
  }
  float vv[4] = {v.x, v.y, v.z, v.w};
  unsigned short hi[4], lo[4];
#pragma unroll
  for (int j = 0; j < 4; ++j){
    hi[j] = f2bf(vv[j]);
    lo[j] = f2bf(vv[j] - bf2f(hi[j]));
  }
  const long off = (long)r * KP + k;
  *(uint2*)(Wh + off) = *(const uint2*)hi;
  *(uint2*)(Wl + off) = *(const uint2*)lo;
}

__global__ __launch_bounds__(256) void k_bias_mu(
    const float* __restrict__ bmu, const float* __restrict__ blv,
    float* __restrict__ bias)
{
  const int i = blockIdx.x * 256 + threadIdx.x;
  if (i < 1024){
    float v = 0.0f;
    if (i < 1000) v = bmu[i];
    else if (i < 1002) v = blv[i - 1000];
    bias[i] = v;
  }
}

// ---------------- mu GEMM: split-bf16 4-term MFMA, 128x64 tiles ----------------
__global__ __launch_bounds__(256) void k_gemm_mf(
    const unsigned short* __restrict__ Ah, const unsigned short* __restrict__ Al,
    const unsigned short* __restrict__ Bh, const unsigned short* __restrict__ Bl,
    const float* __restrict__ bias, float* __restrict__ C)
{
  __shared__ __align__(16) unsigned short sAh[128][40], sAl[128][40];
  __shared__ __align__(16) unsigned short sBh[64][40], sBl[64][40];
  const int tid = threadIdx.x;
  const int cbase = blockIdx.x * 64, rbase = blockIdx.y * 128;
  const int wave = tid >> 6, wm = wave >> 1, wn = wave & 1;
  const int lane = tid & 63, lo = lane & 15, hi4 = lane >> 4;

  using frag = __attribute__((ext_vector_type(8))) short;
  using f32x4 = __attribute__((ext_vector_type(4))) float;
  f32x4 acc[4][2];
#pragma unroll
  for (int a = 0; a < 4; ++a)
#pragma unroll
    for (int c = 0; c < 2; ++c) acc[a][c] = (f32x4){0.f,0.f,0.f,0.f};

  const int arow = tid >> 1, akh = (tid & 1) * 16;
  const int brow = tid >> 2, bkh = (tid & 3) * 8;

  for (int kb = 0; kb < 19; ++kb){
    const int k0 = kb * 32;
    __syncthreads();
    {
      const unsigned short* pa = Ah + (long)(rbase + arow) * KP + k0 + akh;
      *(uint4*)&sAh[arow][akh]     = *(const uint4*)pa;
      *(uint4*)&sAh[arow][akh + 8] = *(const uint4*)(pa + 8);
      const unsigned short* pl = Al + (long)(rbase + arow) * KP + k0 + akh;
      *(uint4*)&sAl[arow][akh]     = *(const uint4*)pl;
      *(uint4*)&sAl[arow][akh + 8] = *(const uint4*)(pl + 8);
      *(uint4*)&sBh[brow][bkh] = *(const uint4*)(Bh + (long)(cbase + brow) * KP + k0 + bkh);
      *(uint4*)&sBl[brow][bkh] = *(const uint4*)(Bl + (long)(cbase + brow) * KP + k0 + bkh);
    }
    __syncthreads();
    frag bh0 = *(const frag*)&sBh[wn*32 + lo][hi4*8];
    frag bh1 = *(const frag*)&sBh[wn*32 + 16 + lo][hi4*8];
    frag bl0 = *(const frag*)&sBl[wn*32 + lo][hi4*8];
    frag bl1 = *(const frag*)&sBl[wn*32 + 16 + lo][hi4*8];
#pragma unroll
    for (int fr = 0; fr < 4; ++fr){
      frag ah = *(const frag*)&sAh[wm*64 + fr*16 + lo][hi4*8];
      frag al = *(const frag*)&sAl[wm*64 + fr*16 + lo][hi4*8];
      acc[fr][0] = __builtin_amdgcn_mfma_f32_16x16x32_bf16(ah, bh0, acc[fr][0], 0, 0, 0);
      acc[fr][0] = __builtin_amdgcn_mfma_f32_16x16x32_bf16(al, bh0, acc[fr][0], 0, 0, 0);
      acc[fr][0] = __builtin_amdgcn_mfma_f32_16x16x32_bf16(ah, bl0, acc[fr][0], 0, 0, 0);
      acc[fr][0] = __builtin_amdgcn_mfma_f32_16x16x32_bf16(al, bl0, acc[fr][0], 0, 0, 0);
      acc[fr][1] = __builtin_amdgcn_mfma_f32_16x16x32_bf16(ah, bh1, acc[fr][1], 0, 0, 0);
      acc[fr][1] = __builtin_amdgcn_mfma_f32_16x16x32_bf16(al, bh1, acc[fr][1], 0, 0, 0);
      acc[fr][1] = __builtin_amdgcn_mfma_f32_16x16x32_bf16(ah, bl1, acc[fr][1], 0, 0, 0);
      acc[fr][1] = __builtin_amdgcn_mfma_f32_16x16x32_bf16(al, bl1, acc[fr][1], 0, 0, 0);
    }
  }
#pragma unroll
  for (int fr = 0; fr < 4; ++fr)
#pragma unroll
    for (int fc = 0; fc < 2; ++fc){
      const int col = cbase + wn*32 + fc*16 + lo;
      if (col < NMU){
        const float bv = bias[col];
        const int r0 = rbase + wm*64 + fr*16 + hi4*4;
#pragma unroll
        for (int j = 0; j < 4; ++j)
          C[(long)(r0 + j) * NMU + col] = acc[fr][fc][j] + bv;
      }
    }
}

// ---------------- stage-1 W pack: 3-way bf16 split, fragment-ready ----------
__global__ __launch_bounds__(256) void k_pack_w3(
    const float* __restrict__ W, unsigned short* __restrict__ Wb3)
{
  const int g = blockIdx.x * 256 + threadIdx.x;   // 16*3*64*80
  if (g >= 245760) return;
  const int k4 = g % 80;
  const int r2 = g / 80;
  const int row = r2 % 64;
  const int r3 = r2 / 64;
  const int s = r3 % 3;
  const int js = r3 / 3;
  const int wid = (js < 15) ? 19 : 15;
  const int jj0 = js * 19;
  unsigned short o4[4];
#pragma unroll
  for (int e = 0; e < 4; ++e){
    const int k = k4 * 4 + e;
    float v = 0.0f;
    if (row < 3 * wid && k < 300){
      const int gate = row / wid, col = row - gate * wid;
      v = W[(long)(gate * 300 + jj0 + col) * 300 + k];
    }
    const unsigned short w1 = f2bf(v);
    const float r1 = v - bf2f(w1);
    const unsigned short w2 = f2bf(r1);
    const float r2f = r1 - bf2f(w2);
    const unsigned short w3 = f2bf(r2f);
    o4[e] = (s == 0) ? w1 : ((s == 1) ? w2 : w3);
  }
  *(uint2*)(Wb3 + ((long)(js * 3 + s) * 64 + row) * 320 + k4 * 4) = *(const uint2*)o4;
}

// ---------------- stage-1: 256 blocks = 16 batch-groups(8 rows) x 16 jj-slices --
#define S1PAD 304

__global__ __launch_bounds__(256, 1) void k_stage1(
    const unsigned short* __restrict__ Wb3, const float* __restrict__ bhh,
    const float* __restrict__ gi_all, float* __restrict__ hx_all,
    float* __restrict__ hex, unsigned int* __restrict__ flagsA)
{
  __shared__ __align__(16) float hs[8][S1PAD];
  __shared__ __align__(16) unsigned short hb[3][8][320];
  __shared__ float ghs[512];
  const int tid = threadIdx.x;
  const int bid = blockIdx.x;
  const int bq = bid >> 4, js = bid & 15;
  const int b0 = bq * 8;
  const int wid = (js < 15) ? 19 : 15;
  const int jj0 = js * 19;
  const int NC = 3 * wid;

  const int wave = tid >> 6, lane = tid & 63;
  const int lo = lane & 15, hi = lane >> 4;

  using frag = __attribute__((ext_vector_type(8))) short;
  using f32x4v = __attribute__((ext_vector_type(4))) float;

  frag wfr[3][10];
  {
    const int row = wave * 16 + lo;
#pragma unroll
    for (int s = 0; s < 3; ++s)
#pragma unroll
      for (int kf = 0; kf < 10; ++kf)
        wfr[s][kf] = *(const frag*)(Wb3 + ((long)(js * 3 + s) * 64 + row) * 320
                                         + kf * 32 + hi * 8);
  }

  const bool gact = tid < 8 * wid;
  const int grow = gact ? (tid / wid) : 0;
  const int gcol = gact ? (tid - grow * wid) : 0;
  const int gjj = jj0 + gcol;
  float bhr = 0.f, bhz = 0.f, bhn = 0.f;
  if (gact){ bhr = bhh[gjj]; bhz = bhh[DD + gjj]; bhn = bhh[2*DD + gjj]; }

  for (int i = tid; i < 8 * S1PAD; i += 256) ((float*)hs)[i] = 0.f;
  for (int i = tid; i < 3840; i += 256) ((unsigned int*)hb)[i] = 0u;
  __syncthreads();

  unsigned int* myflag = flagsA + bid * 16;

  for (int t = 0; t < TT; ++t){
    float gir = 0.f, giz = 0.f, gin = 0.f;
    if (gact){
      const float* gp = gi_all + ((long)t * BB + b0 + grow) * GG;
      gir = gp[gjj]; giz = gp[DD + gjj]; gin = gp[2*DD + gjj];
    }

    f32x4v a0 = {0,0,0,0}, a1 = {0,0,0,0}, a2 = {0,0,0,0};
#pragma unroll
    for (int kf = 0; kf < 10; ++kf){
      frag h1 = *(const frag*)&hb[0][lo & 7][kf * 32 + hi * 8];
      frag h2 = *(const frag*)&hb[1][lo & 7][kf * 32 + hi * 8];
      frag h3 = *(const frag*)&hb[2][lo & 7][kf * 32 + hi * 8];
      a0 = __builtin_amdgcn_mfma_f32_16x16x32_bf16(h1, wfr[0][kf], a0, 0, 0, 0);
      a1 = __builtin_amdgcn_mfma_f32_16x16x32_bf16(h1, wfr[1][kf], a1, 0, 0, 0);
      a2 = __builtin_amdgcn_mfma_f32_16x16x32_bf16(h1, wfr[2][kf], a2, 0, 0, 0);
      a0 = __builtin_amdgcn_mfma_f32_16x16x32_bf16(h2, wfr[0][kf], a0, 0, 0, 0);
      a1 = __builtin_amdgcn_mfma_f32_16x16x32_bf16(h2, wfr[1][kf], a1, 0, 0, 0);
      a2 = __builtin_amdgcn_mfma_f32_16x16x32_bf16(h2, wfr[2][kf], a2, 0, 0, 0);
      a0 = __builtin_amdgcn_mfma_f32_16x16x32_bf16(h3, wfr[0][kf], a0, 0, 0, 0);
      a1 = __builtin_amdgcn_mfma_f32_16x16x32_bf16(h3, wfr[1][kf], a1, 0, 0, 0);
      a2 = __builtin_amdgcn_mfma_f32_16x16x32_bf16(h3, wfr[2][kf], a2, 0, 0, 0);
    }
    {
      const int nc = wave * 16 + lo;
      if (hi < 2 && nc < NC){
#pragma unroll
        for (int j = 0; j < 4; ++j)
          ghs[nc * 8 + hi * 4 + j] = (a0[j] + a1[j]) + a2[j];
      }
    }
    __syncthreads();

    const int par = t & 1;
    if (gact){
      const float r = jsigmoid(gir + ghs[(0 * wid + gcol) * 8 + grow] + bhr);
      const float z = jsigmoid(giz + ghs[(1 * wid + gcol) * 8 + grow] + bhz);
      const float n = tanhf(gin + r * (ghs[(2 * wid + gcol) * 8 + grow] + bhn));
      const float hn = (1.0f - z) * n + z * hs[grow][gjj];
      hx_all[((long)t * BB + b0 + grow) * DD + gjj] = hn;
      if (t < TT - 1)
        store_u32_llc(hex + ((long)par * BB + b0 + grow) * S1PAD + gjj,
                      __float_as_uint(hn));
    }

    if (t < TT - 1){
      asm volatile("s_waitcnt vmcnt(0)" ::: "memory");
      __syncthreads();
      if (tid == 0) store_u32_llc(myflag, (unsigned)(t + 1));
      if (tid < 16){
        const unsigned int* fp = flagsA + (bq * 16 + tid) * 16;
        unsigned v = poll_u32_llc(fp);
        while (v < (unsigned)(t + 1)){
          __builtin_amdgcn_s_sleep(1);
          v = poll_u32_llc(fp);
        }
      }
      __syncthreads();
      {
        const float* src = hex + (long)par * BB * S1PAD + (long)b0 * S1PAD;
        const int gA = tid, gB = tid + 256, gC = tid + 512;
        const int rA = gA / 76, cA = gA - rA * 76;
        const int rB = gB / 76, cB = gB - rB * 76;
        int rC = 0, cC = 0;
        u32x4 vA = load_b128_llc(src + (long)rA * S1PAD + cA * 4);
        u32x4 vB = load_b128_llc(src + (long)rB * S1PAD + cB * 4);
        u32x4 vC = (u32x4){0,0,0,0};
        if (gC < 608){
          rC = gC / 76; cC = gC - rC * 76;
          vC = load_b128_llc(src + (long)rC * S1PAD + cC * 4);
        }
        WAITV(0);
#define CONV_STORE(rr, cc, vv) do{ \
        float f0 = __uint_as_float(vv[0]), f1 = __uint_as_float(vv[1]); \
        float f2v = __uint_as_float(vv[2]), f3 = __uint_as_float(vv[3]); \
        if ((cc) == 75){ f0 = 0.f; f1 = 0.f; f2v = 0.f; f3 = 0.f; } \
        *(u32x4*)&hs[rr][(cc) * 4] = vv; \
        float fv[4] = {f0, f1, f2v, f3}; \
        unsigned short s1[4], s2[4], s3[4]; \
        _Pragma("unroll") \
        for (int j = 0; j < 4; ++j){ \
          s1[j] = f2bf(fv[j]); \
          const float r1 = fv[j] - bf2f(s1[j]); \
          s2[j] = f2bf(r1); \
          s3[j] = f2bf(r1 - bf2f(s2[j])); \
        } \
        *(uint2*)&hb[0][rr][(cc) * 4] = *(const uint2*)s1; \
        *(uint2*)&hb[1][rr][(cc) * 4] = *(const uint2*)s2; \
        *(uint2*)&hb[2][rr][(cc) * 4] = *(const uint2*)s3; \
      }while(0)
        CONV_STORE(rA, cA, vA);
        CONV_STORE(rB, cB, vB);
        if (gC < 608) CONV_STORE(rC, cC, vC);
#undef CONV_STORE
      }
      __syncthreads();
    }
  }
}

// ---------------- sampling (texts written in MFMA-fragment order) ------------
__global__ __launch_bounds__(256) void k_sample(
    const float* __restrict__ X, const float* __restrict__ mu_all,
    unsigned short* __restrict__ tF, float* __restrict__ out,
    const uint32_t k0a, const uint32_t k0b, const uint32_t k1a, const uint32_t k1b,
    const uint32_t k2a, const uint32_t k2b, const uint32_t k3a, const uint32_t k3b)
{
  const int r = blockIdx.x;            // t*128 + b
  const int t = r >> 7, b = r & 127;
  const int tid = threadIdx.x;
  const int h = tid >> 7, lane = tid & 127;
  const int wv = tid >> 6;
  __shared__ float redw[4];
  __shared__ int   redi4[4];
  __shared__ float yw[2], lyw[2], att_s[2];

  const uint32_t rowbase = (uint32_t)((t * 256 + b * 2 + h) * 500);
  float zv[4], ev[4];
  float lmax = -3.0e38f;
#pragma unroll
  for (int s = 0; s < 4; ++s){
    const int a = lane + s * 128;
    float z = -3.0e38f;
    if (a < ASP){
      float g = jgumbel(k0a, k0b, rowbase + (uint32_t)a);
      float m = mu_all[(long)r * NMU + h * ASP + a];
      z = (m + g) / 0.8f;
    }
    zv[s] = z;
    lmax = fmaxf(lmax, z);
  }
  {
    float wm = lmax;
#pragma unroll
    for (int o = 32; o > 0; o >>= 1) wm = fmaxf(wm, __shfl_xor(wm, o));
    if ((tid & 63) == 0) redw[wv] = wm;
  }
  __syncthreads();
  const float mx = fmaxf(redw[h * 2], redw[h * 2 + 1]);
  __syncthreads();

  float lsum = 0.0f;
#pragma unroll
  for (int s = 0; s < 4; ++s){
    const int a = lane + s * 128;
    float e = 0.0f;
    if (a < ASP) e = expf(zv[s] - mx);
    ev[s] = e;
    lsum += e;
  }
  {
    float wsum = lsum;
#pragma unroll
    for (int o = 32; o > 0; o >>= 1) wsum += __shfl_xor(wsum, o);
    if ((tid & 63) == 0) redw[wv] = wsum;
  }
  __syncthreads();
  const float S = redw[h * 2] + redw[h * 2 + 1];
  __syncthreads();

  float bestv = -3.0e38f;
  int besti = 0x7fffffff;
#pragma unroll
  for (int s = 0; s < 4; ++s){
    const int a = lane + s * 128;
    if (a < ASP){
      float y = ev[s] / S;
      float ly = logf(y);
      float gc = jgumbel(k1a, k1b, rowbase + (uint32_t)a);
      float val = ly + gc;
      if (val > bestv){ bestv = val; besti = a; }
    }
  }
  {
    float bv = bestv; int bi = besti;
#pragma unroll
    for (int o = 32; o > 0; o >>= 1){
      float v2 = __shfl_xor(bv, o);
      int   i2 = __shfl_xor(bi, o);
      if (v2 > bv || (v2 == bv && i2 < bi)){ bv = v2; bi = i2; }
    }
    if ((tid & 63) == 0){ redw[wv] = bv; redi4[wv] = bi; }
  }
  __syncthreads();
  int ind;
  {
    const float v0 = redw[h * 2], v1 = redw[h * 2 + 1];
    const int   i0 = redi4[h * 2], i1 = redi4[h * 2 + 1];
    ind = (v1 > v0 || (v1 == v0 && i1 < i0)) ? i1 : i0;
  }
#pragma unroll
  for (int s = 0; s < 4; ++s){
    const int a = lane + s * 128;
    if (a == ind){
      float y = ev[s] / S;
      yw[h] = y;
      lyw[h] = logf(y);
    }
  }
  __syncthreads();
  if (lane == 0){
    const float yv = yw[h];
    const float ly = lyw[h];
    const float yh = (1.0f - yv) + yv;
    const float act = ((float)ind * yh) / 500.0f;
    const float lvr = mu_all[(long)r * NMU + 1000 + h];
    const float lv = fmaxf(lvr, 0.0f) + log1pf(expf(-fabsf(lvr)));
    const float sd = expf(0.5f * lv);
    const uint32_t ei = (uint32_t)(r * 2 + h);
    const float e1 = jnormal(k2a, k2b, ei);
    const float e2 = jnormal(k3a, k3b, ei);
    const float s1 = act + sd * e1;
    const float s2 = act + sd * e2;
    const float dd = (s2 - act) / sd;
    const float lp = -0.5f * (dd * dd) - logf(sd) - 0.9189385332046727f;
    const float attv = 20.0f * jsigmoid(s1);
    out[OUT_SLOG + (long)b * 256 + t * 2 + h]  = ly;
    out[OUT_ACT  + (long)b * 256 + h * 128 + t] = act;
    out[OUT_LOGP + (long)b * 256 + h * 128 + t] = lp;
    att_s[h] = attv;
  }
  __syncthreads();
  const float* xr = X + ((long)b * TT + t) * DD;
  if (tid < 40){
    unsigned short pk[8];
#pragma unroll
    for (int e = 0; e < 8; ++e){
      const int idx = tid * 8 + e;
      float v = 0.0f;
      if (idx < 300) v = xr[idx] * att_s[idx / 150];
      pk[e] = f2bf(v);
    }
    unsigned short* dst = tF + (((long)t * 8 + (b >> 4)) * 40 + tid) * 128
                             + (b & 15) * 8;
    *(uint4*)dst = *(const uint4*)pk;
  }
}

// ---------------- weight conversion to bf16 (stage-2) ----------------
__global__ __launch_bounds__(256) void k_cvt_whh(
    const float* __restrict__ W, unsigned short* __restrict__ O)
{
  const int i = blockIdx.x * 256 + threadIdx.x;   // 3072*1024
  O[i] = f2bf(W[i]);
}

__global__ __launch_bounds__(256) void k_cvt_wih(
    const float* __restrict__ W, unsigned short* __restrict__ O)
{
  const int i = blockIdx.x * 256 + threadIdx.x;   // 3072*320
  const int rw = i / 320, c = i - rw * 320;
  O[i] = (c < DD) ? f2bf(W[(long)rw * DD + c]) : (unsigned short)0;
}

// ---------------- stage-2 persistent: 128 blocks x 512 thr (R17 revert) --------
#define NBLK2 128
#define WPITCH 2704   // 1344*2 + 16

__global__ __launch_bounds__(512) void k_stage2(
    const unsigned short* __restrict__ tF,
    const unsigned short* __restrict__ Whb,
    const unsigned short* __restrict__ Wib,
    const float* __restrict__ bih, const float* __restrict__ bhh,
    const int* __restrict__ lengths,
    unsigned short* __restrict__ hF0, unsigned short* __restrict__ hF1,
    float* __restrict__ last,
    unsigned int* __restrict__ flags)
{
  __shared__ __align__(16) char lds[152320];   // W:129792 | reduce:20480 | Tl:2048
  unsigned short* Wl = (unsigned short*)lds;
  char* Al = lds + 129792;
  unsigned short* Tl = (unsigned short*)(lds + 150272);

  const int tid = threadIdx.x;
  const int bid = blockIdx.x;
  const int m = bid >> 6, n = bid & 63;
  const int e0 = n * 16, mrow = m * 64;
  const int wave = tid >> 6, wg = wave >> 2, wvr = wave & 3;
  const int lane = tid & 63, lo = lane & 15, hi = lane >> 4;
  const int tidg = tid & 255;

  for (int s = tid; s < 48 * 168; s += 512){
    const int row = s / 168, q = s - row * 168;
    const int g = row >> 4, nn = row & 15;
    const long wrow = (long)g * EE + e0 + nn;
    uint4 v;
    if (q < 128) v = *(const uint4*)(Whb + wrow * EE + q * 8);
    else         v = *(const uint4*)(Wib + wrow * 320 + (q - 128) * 8);
    *(uint4*)((char*)Wl + (long)row * WPITCH + q * 16) = v;
  }

  const int e = e0 + lo;
  const float bR = bih[e] + bhh[e];
  const float bZ = bih[EE + e] + bhh[EE + e];
  const float biN = bih[2*EE + e];
  const float bhN = bhh[2*EE + e];
  int li[4]; float hp[4];
#pragma unroll
  for (int j = 0; j < 4; ++j){
    const int brow = wvr * 16 + hi * 4 + j;
    int l = lengths[mrow + brow] - 1; if (l < 0) l += TT;
    li[j] = l; hp[j] = 0.0f;
  }
  __syncthreads();

  using frag = __attribute__((ext_vector_type(8))) short;
  using f32x4 = __attribute__((ext_vector_type(4))) float;

  const int rg = m * 4 + wvr;
  int boff[3];
#pragma unroll
  for (int g = 0; g < 3; ++g) boff[g] = (g * 16 + lo) * WPITCH + hi * 16;

  const long tBase = ((long)rg * 40 + (wg ? 24 : 0) + hi) * 128 + lo * 8;
  const long hBase = (long)rg * 16384 + (long)(wg * 64 + hi) * 128 + lo * 8;

  unsigned int* flagp = flags + (m << 6) + n;

  for (int t = 0; t < TT; ++t){
    const unsigned short* hFin = (t & 1) ? hF1 : hF0;
    unsigned short* hFout = (t & 1) ? hF0 : hF1;
    const unsigned short* tA = tF + (long)t * 8 * 40 * 128 + tBase;
    const unsigned short* hA = hFin + hBase;

    f32x4 aR = {0,0,0,0}, aZ = {0,0,0,0}, aNH = {0,0,0,0}, aNI = {0,0,0,0};

    auto chunkD = [&](int cc, u32x4 a0v, u32x4 a1v, bool hid){
      frag a0 = *(frag*)&a0v;
      frag a1 = *(frag*)&a1v;
      const char* wb = (const char*)Wl + cc * 128;
      frag b00 = *(const frag*)(wb + boff[0]);
      frag b10 = *(const frag*)(wb + boff[1]);
      frag b20 = *(const frag*)(wb + boff[2]);
      frag b01 = *(const frag*)(wb + boff[0] + 64);
      frag b11 = *(const frag*)(wb + boff[1] + 64);
      frag b21 = *(const frag*)(wb + boff[2] + 64);
      aR = __builtin_amdgcn_mfma_f32_16x16x32_bf16(a0, b00, aR, 0, 0, 0);
      aZ = __builtin_amdgcn_mfma_f32_16x16x32_bf16(a0, b10, aZ, 0, 0, 0);
      if (hid) aNH = __builtin_amdgcn_mfma_f32_16x16x32_bf16(a0, b20, aNH, 0, 0, 0);
      else     aNI = __builtin_amdgcn_mfma_f32_16x16x32_bf16(a0, b20, aNI, 0, 0, 0);
      aR = __builtin_amdgcn_mfma_f32_16x16x32_bf16(a1, b01, aR, 0, 0, 0);
      aZ = __builtin_amdgcn_mfma_f32_16x16x32_bf16(a1, b11, aZ, 0, 0, 0);
      if (hid) aNH = __builtin_amdgcn_mfma_f32_16x16x32_bf16(a1, b21, aNH, 0, 0, 0);
      else     aNI = __builtin_amdgcn_mfma_f32_16x16x32_bf16(a1, b21, aNI, 0, 0, 0);
    };

    {
      u32x4 t0a = load_b128_llc(tA);
      u32x4 t0b = load_b128_llc(tA + 512);
      u32x4 t1a = load_b128_llc(tA + 1024);
      u32x4 t1b = load_b128_llc(tA + 1536);
      if (wg == 0){
        u32x4 t2a = load_b128_llc(tA + 2048);
        u32x4 t2b = load_b128_llc(tA + 2560);
        WAITV(4); chunkD(16, t0a, t0b, false);
        WAITV(2); chunkD(17, t1a, t1b, false);
        WAITV(0); chunkD(18, t2a, t2b, false);
      } else {
        WAITV(2); chunkD(19, t0a, t0b, false);
        WAITV(0); chunkD(20, t1a, t1b, false);
      }
    }

    if (t > 0){
      if (tid < 16){
        const unsigned int* fp = flags + (m << 6) + tid * 4;
        for (;;){
          u32x4 f = load_b128_llc(fp);
          WAITV(0);
          if (f[0] >= (unsigned)t && f[1] >= (unsigned)t &&
              f[2] >= (unsigned)t && f[3] >= (unsigned)t) break;
          __builtin_amdgcn_s_sleep(2);
        }
      }
      __syncthreads();

      u32x4 h0a = load_b128_llc(hA +    0), h0b = load_b128_llc(hA +  512);
      u32x4 h1a = load_b128_llc(hA + 1024), h1b = load_b128_llc(hA + 1536);
      u32x4 h2a = load_b128_llc(hA + 2048), h2b_ = load_b128_llc(hA + 2560);
      u32x4 h3a = load_b128_llc(hA + 3072), h3b = load_b128_llc(hA + 3584);
      u32x4 h4a = load_b128_llc(hA + 4096), h4b = load_b128_llc(hA + 4608);
      u32x4 h5a = load_b128_llc(hA + 5120), h5b = load_b128_llc(hA + 5632);
      u32x4 h6a = load_b128_llc(hA + 6144), h6b = load_b128_llc(hA + 6656);
      u32x4 h7a = load_b128_llc(hA + 7168), h7b = load_b128_llc(hA + 7680);
      const int cb = wg * 8;
      WAITV(14); chunkD(cb + 0, h0a, h0b, true);
      WAITV(12); chunkD(cb + 1, h1a, h1b, true);
      WAITV(10); chunkD(cb + 2, h2a, h2b_, true);
      WAITV(8);  chunkD(cb + 3, h3a, h3b, true);
      WAITV(6);  chunkD(cb + 4, h4a, h4b, true);
      WAITV(4);  chunkD(cb + 5, h5a, h5b, true);
      WAITV(2);  chunkD(cb + 6, h6a, h6b, true);
      WAITV(0);  chunkD(cb + 7, h7a, h7b, true);
    }

    __syncthreads();
    if (wg == 1){
      char* dst = Al + tidg * 80;
      *(f32x4*)(dst)      = aR;
      *(f32x4*)(dst + 16) = aZ;
      *(f32x4*)(dst + 32) = aNH;
      *(f32x4*)(dst + 48) = aNI;
    }
    __syncthreads();
    if (wg == 0){
      const char* src = Al + tidg * 80;
      const f32x4 pR  = *(const f32x4*)(src);
      const f32x4 pZ  = *(const f32x4*)(src + 16);
      const f32x4 pNH = *(const f32x4*)(src + 32);
      const f32x4 pNI = *(const f32x4*)(src + 48);
#pragma unroll
      for (int j = 0; j < 4; ++j){
        aR[j] += pR[j]; aZ[j] += pZ[j]; aNH[j] += pNH[j]; aNI[j] += pNI[j];
      }
#pragma unroll
      for (int j = 0; j < 4; ++j){
        const int brow = wvr * 16 + hi * 4 + j;
        const float r = jsigmoid(aR[j] + bR);
        const float z = jsigmoid(aZ[j] + bZ);
        const float nn2 = tanhf(aNI[j] + biN + r * (aNH[j] + bhN));
        const float hn = (1.0f - z) * nn2 + z * hp[j];
        hp[j] = hn;
        Tl[brow * 16 + lo] = f2bf(hn);
        if (t == li[j]) last[(long)(mrow + brow) * EE + e] = hn;
      }
    }

    if (t < TT - 1){
      __syncthreads();
      if (tid < 128){
        const int rgp = tid >> 5;
        const int kbp = (tid >> 4) & 1;
        const int lop = tid & 15;
        u32x4 v = *(const u32x4*)(Tl + (rgp * 16 + lop) * 16 + kbp * 8);
        store_b128_llc(hFout + ((long)(m * 4 + rgp) * 128 + (n * 2 + kbp)) * 128
                             + lop * 8, v);
      }
      asm volatile("s_waitcnt vmcnt(0)" ::: "memory");
      __syncthreads();
      if (tid == 0) store_u32_llc(flagp, (unsigned)(t + 1));
    }
  }
}

// ---------------- BatchNorm ----------------
__global__ __launch_bounds__(256) void k_bn_stats(
    const float* __restrict__ last, float* __restrict__ mv)
{
  const int e = blockIdx.x * 256 + threadIdx.x;
  if (e >= EE) return;
  float s = 0.0f;
  for (int b = 0; b < BB; ++b) s += last[(long)b * EE + e];
  const float mean = s / 128.0f;
  float v = 0.0f;
  for (int b = 0; b < BB; ++b){ float d = last[(long)b * EE + e] - mean; v += d * d; }
  mv[e] = mean;
  mv[EE + e] = v / 128.0f;
}

__global__ __launch_bounds__(256) void k_bn_apply(
    const float* __restrict__ last, const float* __restrict__ mv,
    const float* __restrict__ gamma, const float* __restrict__ beta,
    float* __restrict__ out)
{
  const int gid = blockIdx.x * 256 + threadIdx.x;
  const int e = gid & 1023;
  const float xm = last[gid] - mv[e];
  out[gid] = gamma[e] * xm / sqrtf(mv[EE + e] + 1e-5f) + beta[e];
}

// ---------------- launcher ----------------
extern "C" void kernel_launch(void* const* d_in, const int* in_sizes, int n_in,
                              void* d_out, int out_size, void* d_ws, size_t ws_size,
                              hipStream_t stream)
{
  (void)in_sizes; (void)n_in; (void)out_size;
  const float* x     = (const float*)d_in[0];
  const int*   lens  = (const int*)d_in[1];
  const float* Wih_c = (const float*)d_in[3];
  const float* Whh_c = (const float*)d_in[4];
  const float* bih_c = (const float*)d_in[5];
  const float* bhh_c = (const float*)d_in[6];
  const float* Wmu   = (const float*)d_in[7];
  const float* bmu   = (const float*)d_in[8];
  const float* Wlv   = (const float*)d_in[9];
  const float* blv   = (const float*)d_in[10];
  const float* Wih_r = (const float*)d_in[11];
  const float* Whh_r = (const float*)d_in[12];
  const float* bih_r = (const float*)d_in[13];
  const float* bhh_r = (const float*)d_in[14];
  const float* gam   = (const float*)d_in[15];
  const float* bet   = (const float*)d_in[16];
  float* out = (float*)d_out;

  uint32_t nk[4][2];
  for (uint32_t i = 0; i < 4; ++i) tf2x32(0u, 42u, 0u, i, &nk[i][0], &nk[i][1]);

  float* ws = (float*)d_ws;
  size_t off = 0;
  float* U       = ws + off; off += 16515072;  // gi_all then mu_all[16384][1008]
  float* hx_all  = ws + off; off += 4915200;
  float* lastb   = ws + off; off += 131072;
  float* mv      = ws + off; off += 2048;
  float* hex     = ws + off; off += 77824;     // [2][128][304] f32 stage-1 exchange
  float* biasM   = ws + off; off += 1024;      // fused mu+lv bias
  unsigned int* flags  = (unsigned int*)(ws + off); off += 2048;  // stage-2 packed [m][64]
  unsigned int* flagsA = (unsigned int*)(ws + off); off += 4096;  // stage-1: 256*16
  unsigned short* tF  = (unsigned short*)(ws + off); off += 2621440; // texts frag order
  unsigned short* hF0 = (unsigned short*)(ws + off); off += 65536;
  unsigned short* hF1 = (unsigned short*)(ws + off); off += 65536;
  unsigned short* Whb = (unsigned short*)(ws + off); off += 1572864; // 3072x1024 bf16
  unsigned short* Wib = (unsigned short*)(ws + off); off += 491520;  // 3072x320 bf16
  unsigned short* Wb3 = (unsigned short*)(ws + off); off += 491520;  // [16][3][64][320] bf16
  unsigned short* WmH = (unsigned short*)(ws + off); off += 311296;  // 1024x608 bf16
  unsigned short* WmL = (unsigned short*)(ws + off); off += 311296;
  unsigned short* AmH = (unsigned short*)(ws + off); off += 4980736; // 16384x608 bf16
  unsigned short* AmL = (unsigned short*)(ws + off); off += 4980736;
  unsigned short* AgH = (unsigned short*)(ws + off); off += 2621440; // 16384x320 bf16
  unsigned short* AgL = (unsigned short*)(ws + off); off += 2621440;
  unsigned short* WgH = (unsigned short*)(ws + off); off += 153600;  // 960x320 bf16
  unsigned short* WgL = (unsigned short*)(ws + off); off += 153600;
  if (ws_size < off * sizeof(float)) return;

  hipMemsetAsync(flags, 0, 2048 * sizeof(unsigned int), stream);
  hipMemsetAsync(flagsA, 0, 4096 * sizeof(unsigned int), stream);

  // weight prep
  k_cvt_whh<<<dim3(12288), 256, 0, stream>>>(Whh_r, Whb);
  k_cvt_wih<<<dim3(3840), 256, 0, stream>>>(Wih_r, Wib);
  k_pack_w3<<<dim3(960), 256, 0, stream>>>(Whh_c, Wb3);
  k_cvt_Wmu<<<dim3(608), 256, 0, stream>>>(Wmu, Wlv, WmH, WmL);
  k_bias_mu<<<dim3(4), 256, 0, stream>>>(bmu, blv, biasM);
  k_cvt_Wgi<<<dim3(300), 256, 0, stream>>>(Wih_c, WgH, WgL);

  // stage-1 input projection (split-bf16 MFMA) + persistent MFMA recurrence
  k_cvt_Ax<<<dim3(5120), 256, 0, stream>>>(x, AgH, AgL);
  k_gemm_gf<<<dim3(15, 128), 256, 0, stream>>>(AgH, AgL, WgH, WgL, bih_c, U);
  k_stage1<<<dim3(256), 256, 0, stream>>>(Wb3, bhh_c, U, hx_all, hex, flagsA);

  // mu+lv via split-bf16 4-term MFMA, then sampling
  k_cvt_Amu<<<dim3(9728), 256, 0, stream>>>(x, hx_all, AmH, AmL);
  k_gemm_mf<<<dim3(16, 128), 256, 0, stream>>>(AmH, AmL, WmH, WmL, biasM, U);
  k_sample<<<dim3(16384), 256, 0, stream>>>(x, U, tF, out,
      nk[0][0], nk[0][1], nk[1][0], nk[1][1],
      nk[2][0], nk[2][1], nk[3][0], nk[3][1]);

  // stage-2 persistent recurrence (R17 schedule: frag-ordered A, B LDS-resident)
  k_stage2<<<dim3(NBLK2), 512, 0, stream>>>(tF, Whb, Wib, bih_r, bhh_r, lens,
                                            hF0, hF1, lastb, flags);

  // batchnorm
  k_bn_stats<<<dim3(4), 256, 0, stream>>>(lastb, mv);
  k_bn_apply<<<dim3(512), 256, 0, stream>>>(lastb, mv, gam, bet, out);
}

// Round 20
// 1409.795 us; speedup vs baseline: 1.4172x; 1.0068x over previous
//
#include <hip/hip_runtime.h>
#include <stdint.h>

#define TT 128
#define BB 128
#define DD 300
#define EE 1024
#define GG 900
#define NMU 1008
#define ASP 500
#define KP 608

#define OUT_SLOG 131072
#define OUT_ACT  163840
#define OUT_LOGP 196608

typedef unsigned int u32x4 __attribute__((ext_vector_type(4)));

// ---------------- threefry2x32 (JAX, 20 rounds) ----------------
__host__ __device__ static inline uint32_t rotl32(uint32_t x, int r){
  return (x << r) | (x >> (32 - r));
}

__host__ __device__ static inline void tf2x32(uint32_t k0, uint32_t k1,
                                              uint32_t x0, uint32_t x1,
                                              uint32_t* o0, uint32_t* o1){
  uint32_t ks2 = k0 ^ k1 ^ 0x1BD11BDAu;
#define TFR(r) { x0 += x1; x1 = rotl32(x1, r); x1 ^= x0; }
  x0 += k0; x1 += k1;
  TFR(13) TFR(15) TFR(26) TFR(6)
  x0 += k1; x1 += ks2 + 1u;
  TFR(17) TFR(29) TFR(16) TFR(24)
  x0 += ks2; x1 += k0 + 2u;
  TFR(13) TFR(15) TFR(26) TFR(6)
  x0 += k0; x1 += k1 + 3u;
  TFR(17) TFR(29) TFR(16) TFR(24)
  x0 += k1; x1 += ks2 + 4u;
  TFR(13) TFR(15) TFR(26) TFR(6)
  x0 += ks2; x1 += k0 + 5u;
#undef TFR
  *o0 = x0; *o1 = x1;
}

__device__ static inline uint32_t rng32(uint32_t k0, uint32_t k1, uint32_t idx){
  uint32_t a, b;
  tf2x32(k0, k1, 0u, idx, &a, &b);
  return a ^ b;
}

__device__ static inline float u01(uint32_t bits){
  return __uint_as_float((bits >> 9) | 0x3f800000u) - 1.0f;
}

__device__ static inline float jgumbel(uint32_t k0, uint32_t k1, uint32_t idx){
  float u = u01(rng32(k0, k1, idx));
  float l1 = logf(u + 1e-20f);
  return -logf(-l1 + 1e-20f);
}

__device__ static inline float erfinv32(float x){   // XLA ErfInv32 (Giles)
  float w = -log1pf(-x * x);
  float p;
  if (w < 5.0f){
    w = w - 2.5f;
    p = 2.81022636e-08f;
    p = 3.43273939e-07f  + p * w;
    p = -3.5233877e-06f  + p * w;
    p = -4.39150654e-06f + p * w;
    p = 0.00021858087f   + p * w;
    p = -0.00125372503f  + p * w;
    p = -0.00417768164f  + p * w;
    p = 0.246640727f     + p * w;
    p = 1.50140941f      + p * w;
  } else {
    w = sqrtf(w) - 3.0f;
    p = -0.000200214257f;
    p = 0.000100950558f  + p * w;
    p = 0.00134934322f   + p * w;
    p = -0.00367342844f  + p * w;
    p = 0.00573950773f   + p * w;
    p = -0.0076224613f   + p * w;
    p = 0.00943887047f   + p * w;
    p = 1.00167406f      + p * w;
    p = 2.83297682f      + p * w;
  }
  return p * x;
}

__device__ static inline float jnormal(uint32_t k0, uint32_t k1, uint32_t idx){
  float u = u01(rng32(k0, k1, idx));
  const float lo = -0.99999994f;
  float v = u * 2.0f + lo;
  v = fmaxf(lo, v);
  return 1.41421356237f * erfinv32(v);
}

__device__ static inline float jsigmoid(float x){
  return 1.0f / (1.0f + expf(-x));
}

__device__ static inline unsigned short f2bf(float f){   // RNE f32->bf16
  uint32_t u = __float_as_uint(f);
  uint32_t r = (u + 0x7fffu + ((u >> 16) & 1u)) >> 16;
  return (unsigned short)r;
}
__device__ static inline float bf2f(unsigned short h){
  return __uint_as_float((uint32_t)h << 16);
}

// ---- LLC-coherent (cross-XCD) memory ops: sc0 sc1 = bypass L1+L2 ----
__device__ static inline u32x4 load_b128_llc(const void* p){
  u32x4 r;
  asm volatile("global_load_dwordx4 %0, %1, off sc0 sc1"
               : "=v"(r) : "v"(p) : "memory");
  return r;
}
__device__ static inline void store_b128_llc(void* p, u32x4 v){
  asm volatile("global_store_dwordx4 %0, %1, off sc0 sc1"
               :: "v"(p), "v"(v) : "memory");
}
__device__ static inline unsigned poll_u32_llc(const void* p){
  unsigned r;
  asm volatile("global_load_dword %0, %1, off sc0 sc1\n\ts_waitcnt vmcnt(0)"
               : "=v"(r) : "v"(p) : "memory");
  return r;
}
__device__ static inline void store_u32_llc(void* p, unsigned v){
  asm volatile("global_store_dword %0, %1, off sc0 sc1"
               :: "v"(p), "v"(v) : "memory");
}

#define WAITV(N) do{ asm volatile("s_waitcnt vmcnt(" #N ")" ::: "memory"); \
                     __builtin_amdgcn_sched_barrier(0); }while(0)

// ---------------- merged x conversions: gi A (no relu) + mu A x-half (relu) ----
__global__ __launch_bounds__(256) void k_cvt_Axm(
    const float* __restrict__ X,
    unsigned short* __restrict__ AgH, unsigned short* __restrict__ AgL,
    unsigned short* __restrict__ AmH, unsigned short* __restrict__ AmL)
{
  const long i = (long)blockIdx.x * 256 + threadIdx.x;   // 16384*80
  const int r = (int)(i / 80), g = (int)(i - (long)r * 80);
  const int k = g * 4;
  const int b = r & 127, t = r >> 7;
  float4 v = {0,0,0,0};
  if (k < 300) v = *(const float4*)(X + ((long)b * TT + t) * DD + k);
  float vv[4] = {v.x, v.y, v.z, v.w};
  unsigned short gh[4], gl[4], mh[4], ml[4];
#pragma unroll
  for (int j = 0; j < 4; ++j){
    gh[j] = f2bf(vv[j]);
    gl[j] = f2bf(vv[j] - bf2f(gh[j]));
    const float rv = fmaxf(vv[j], 0.0f);
    mh[j] = f2bf(rv);
    ml[j] = f2bf(rv - bf2f(mh[j]));
  }
  const long goff = (long)r * 320 + k;
  *(uint2*)(AgH + goff) = *(const uint2*)gh;
  *(uint2*)(AgL + goff) = *(const uint2*)gl;
  if (k < 300){
    const long moff = (long)r * KP + k;
    *(uint2*)(AmH + moff) = *(const uint2*)mh;
    *(uint2*)(AmL + moff) = *(const uint2*)ml;
  } else if (g == 76 || g == 77){
    // zero-pad mu cols 600..607
    const long moff = (long)r * KP + 600 + (g - 76) * 4;
    const uint2 z = {0u, 0u};
    *(uint2*)(AmH + moff) = z;
    *(uint2*)(AmL + moff) = z;
  }
}

// Wg[960][320] = [Wih_c(900x300); 0], hi/lo bf16
__global__ __launch_bounds__(256) void k_cvt_Wgi(
    const float* __restrict__ W,
    unsigned short* __restrict__ Wh, unsigned short* __restrict__ Wl)
{
  const int i = blockIdx.x * 256 + threadIdx.x;   // 960*80
  if (i >= 76800) return;
  const int r = i / 80, g = i - r * 80;
  const int k = g * 4;
  float4 v = {0,0,0,0};
  if (k < 300 && r < 900) v = *(const float4*)(W + (long)r * DD + k);
  float vv[4] = {v.x, v.y, v.z, v.w};
  unsigned short hi[4], lo[4];
#pragma unroll
  for (int j = 0; j < 4; ++j){
    hi[j] = f2bf(vv[j]);
    lo[j] = f2bf(vv[j] - bf2f(hi[j]));
  }
  const long off = (long)r * 320 + k;
  *(uint2*)(Wh + off) = *(const uint2*)hi;
  *(uint2*)(Wl + off) = *(const uint2*)lo;
}

// ---------------- gi GEMM: split-bf16 4-term MFMA, 128x64 tiles, K=320 -------
__global__ __launch_bounds__(256) void k_gemm_gf(
    const unsigned short* __restrict__ Ah, const unsigned short* __restrict__ Al,
    const unsigned short* __restrict__ Bh, const unsigned short* __restrict__ Bl,
    const float* __restrict__ bias, float* __restrict__ C)
{
  __shared__ __align__(16) unsigned short sAh[128][40], sAl[128][40];
  __shared__ __align__(16) unsigned short sBh[64][40], sBl[64][40];
  const int tid = threadIdx.x;
  const int cbase = blockIdx.x * 64, rbase = blockIdx.y * 128;
  const int wave = tid >> 6, wm = wave >> 1, wn = wave & 1;
  const int lane = tid & 63, lo = lane & 15, hi4 = lane >> 4;

  using frag = __attribute__((ext_vector_type(8))) short;
  using f32x4 = __attribute__((ext_vector_type(4))) float;
  f32x4 acc[4][2];
#pragma unroll
  for (int a = 0; a < 4; ++a)
#pragma unroll
    for (int c = 0; c < 2; ++c) acc[a][c] = (f32x4){0.f,0.f,0.f,0.f};

  const int arow = tid >> 1, akh = (tid & 1) * 16;
  const int brow = tid >> 2, bkh = (tid & 3) * 8;

  for (int kb = 0; kb < 10; ++kb){
    const int k0 = kb * 32;
    __syncthreads();
    {
      const unsigned short* pa = Ah + (long)(rbase + arow) * 320 + k0 + akh;
      *(uint4*)&sAh[arow][akh]     = *(const uint4*)pa;
      *(uint4*)&sAh[arow][akh + 8] = *(const uint4*)(pa + 8);
      const unsigned short* pl = Al + (long)(rbase + arow) * 320 + k0 + akh;
      *(uint4*)&sAl[arow][akh]     = *(const uint4*)pl;
      *(uint4*)&sAl[arow][akh + 8] = *(const uint4*)(pl + 8);
      *(uint4*)&sBh[brow][bkh] = *(const uint4*)(Bh + (long)(cbase + brow) * 320 + k0 + bkh);
      *(uint4*)&sBl[brow][bkh] = *(const uint4*)(Bl + (long)(cbase + brow) * 320 + k0 + bkh);
    }
    __syncthreads();
    frag bh0 = *(const frag*)&sBh[wn*32 + lo][hi4*8];
    frag bh1 = *(const frag*)&sBh[wn*32 + 16 + lo][hi4*8];
    frag bl0 = *(const frag*)&sBl[wn*32 + lo][hi4*8];
    frag bl1 = *(const frag*)&sBl[wn*32 + 16 + lo][hi4*8];
#pragma unroll
    for (int fr = 0; fr < 4; ++fr){
      frag ah = *(const frag*)&sAh[wm*64 + fr*16 + lo][hi4*8];
      frag al = *(const frag*)&sAl[wm*64 + fr*16 + lo][hi4*8];
      acc[fr][0] = __builtin_amdgcn_mfma_f32_16x16x32_bf16(ah, bh0, acc[fr][0], 0, 0, 0);
      acc[fr][0] = __builtin_amdgcn_mfma_f32_16x16x32_bf16(al, bh0, acc[fr][0], 0, 0, 0);
      acc[fr][0] = __builtin_amdgcn_mfma_f32_16x16x32_bf16(ah, bl0, acc[fr][0], 0, 0, 0);
      acc[fr][0] = __builtin_amdgcn_mfma_f32_16x16x32_bf16(al, bl0, acc[fr][0], 0, 0, 0);
      acc[fr][1] = __builtin_amdgcn_mfma_f32_16x16x32_bf16(ah, bh1, acc[fr][1], 0, 0, 0);
      acc[fr][1] = __builtin_amdgcn_mfma_f32_16x16x32_bf16(al, bh1, acc[fr][1], 0, 0, 0);
      acc[fr][1] = __builtin_amdgcn_mfma_f32_16x16x32_bf16(ah, bl1, acc[fr][1], 0, 0, 0);
      acc[fr][1] = __builtin_amdgcn_mfma_f32_16x16x32_bf16(al, bl1, acc[fr][1], 0, 0, 0);
    }
  }
#pragma unroll
  for (int fr = 0; fr < 4; ++fr)
#pragma unroll
    for (int fc = 0; fc < 2; ++fc){
      const int col = cbase + wn*32 + fc*16 + lo;
      if (col < GG){
        const float bv = bias[col];
        const int r0 = rbase + wm*64 + fr*16 + hi4*4;
#pragma unroll
        for (int j = 0; j < 4; ++j)
          C[(long)(r0 + j) * GG + col] = acc[fr][fc][j] + bv;
      }
    }
}

// ---------------- mu weight conversions ----------------
__global__ __launch_bounds__(256) void k_cvt_Wmu(
    const float* __restrict__ Wmu, const float* __restrict__ Wlv,
    unsigned short* __restrict__ Wh, unsigned short* __restrict__ Wl)
{
  const long i = (long)blockIdx.x * 256 + threadIdx.x;   // 1024*152 groups
  const int r = (int)(i / 152), g = (int)(i - (long)r * 152);
  const int k = g * 4;
  float4 v = {0,0,0,0};
  if (k < 600){
    if (r < 1000)      v = *(const float4*)(Wmu + (long)r * 600 + k);
    else if (r < 1002) v = *(const float4*)(Wlv + (long)(r - 1000) * 600 + k);
  }
  float vv[4] = {v.x, v.y, v.z, v.w};
  unsigned short hi[4], lo[4];
#pragma unroll
  for (int j = 0; j < 4; ++j){
    hi[j] = f2bf(vv[j]);
    lo[j] = f2bf(vv[j] - bf2f(hi[j]));
  }
  const long off = (long)r * KP + k;
  *(uint2*)(Wh + off) = *(const uint2*)hi;
  *(uint2*)(Wl + off) = *(const uint2*)lo;
}

__global__ __launch_bounds__(256) void k_bias_mu(
    const float* __restrict__ bmu, const float* __restrict__ blv,
    float* __restrict__ bias)
{
  const int i = blockIdx.x * 256 + threadIdx.x;
  if (i < 1024){
    float v = 0.0f;
    if (i < 1000) v = bmu[i];
    else if (i < 1002) v = blv[i - 1000];
    bias[i] = v;
  }
}

// ---------------- mu GEMM: split-bf16 4-term MFMA, 128x64 tiles ----------------
__global__ __launch_bounds__(256) void k_gemm_mf(
    const unsigned short* __restrict__ Ah, const unsigned short* __restrict__ Al,
    const unsigned short* __restrict__ Bh, const unsigned short* __restrict__ Bl,
    const float* __restrict__ bias, float* __restrict__ C)
{
  __shared__ __align__(16) unsigned short sAh[128][40], sAl[128][40];
  __shared__ __align__(16) unsigned short sBh[64][40], sBl[64][40];
  const int tid = threadIdx.x;
  const int cbase = blockIdx.x * 64, rbase = blockIdx.y * 128;
  const int wave = tid >> 6, wm = wave >> 1, wn = wave & 1;
  const int lane = tid & 63, lo = lane & 15, hi4 = lane >> 4;

  using frag = __attribute__((ext_vector_type(8))) short;
  using f32x4 = __attribute__((ext_vector_type(4))) float;
  f32x4 acc[4][2];
#pragma unroll
  for (int a = 0; a < 4; ++a)
#pragma unroll
    for (int c = 0; c < 2; ++c) acc[a][c] = (f32x4){0.f,0.f,0.f,0.f};

  const int arow = tid >> 1, akh = (tid & 1) * 16;
  const int brow = tid >> 2, bkh = (tid & 3) * 8;

  for (int kb = 0; kb < 19; ++kb){
    const int k0 = kb * 32;
    __syncthreads();
    {
      const unsigned short* pa = Ah + (long)(rbase + arow) * KP + k0 + akh;
      *(uint4*)&sAh[arow][akh]     = *(const uint4*)pa;
      *(uint4*)&sAh[arow][akh + 8] = *(const uint4*)(pa + 8);
      const unsigned short* pl = Al + (long)(rbase + arow) * KP + k0 + akh;
      *(uint4*)&sAl[arow][akh]     = *(const uint4*)pl;
      *(uint4*)&sAl[arow][akh + 8] = *(const uint4*)(pl + 8);
      *(uint4*)&sBh[brow][bkh] = *(const uint4*)(Bh + (long)(cbase + brow) * KP + k0 + bkh);
      *(uint4*)&sBl[brow][bkh] = *(const uint4*)(Bl + (long)(cbase + brow) * KP + k0 + bkh);
    }
    __syncthreads();
    frag bh0 = *(const frag*)&sBh[wn*32 + lo][hi4*8];
    frag bh1 = *(const frag*)&sBh[wn*32 + 16 + lo][hi4*8];
    frag bl0 = *(const frag*)&sBl[wn*32 + lo][hi4*8];
    frag bl1 = *(const frag*)&sBl[wn*32 + 16 + lo][hi4*8];
#pragma unroll
    for (int fr = 0; fr < 4; ++fr){
      frag ah = *(const frag*)&sAh[wm*64 + fr*16 + lo][hi4*8];
      frag al = *(const frag*)&sAl[wm*64 + fr*16 + lo][hi4*8];
      acc[fr][0] = __builtin_amdgcn_mfma_f32_16x16x32_bf16(ah, bh0, acc[fr][0], 0, 0, 0);
      acc[fr][0] = __builtin_amdgcn_mfma_f32_16x16x32_bf16(al, bh0, acc[fr][0], 0, 0, 0);
      acc[fr][0] = __builtin_amdgcn_mfma_f32_16x16x32_bf16(ah, bl0, acc[fr][0], 0, 0, 0);
      acc[fr][0] = __builtin_amdgcn_mfma_f32_16x16x32_bf16(al, bl0, acc[fr][0], 0, 0, 0);
      acc[fr][1] = __builtin_amdgcn_mfma_f32_16x16x32_bf16(ah, bh1, acc[fr][1], 0, 0, 0);
      acc[fr][1] = __builtin_amdgcn_mfma_f32_16x16x32_bf16(al, bh1, acc[fr][1], 0, 0, 0);
      acc[fr][1] = __builtin_amdgcn_mfma_f32_16x16x32_bf16(ah, bl1, acc[fr][1], 0, 0, 0);
      acc[fr][1] = __builtin_amdgcn_mfma_f32_16x16x32_bf16(al, bl1, acc[fr][1], 0, 0, 0);
    }
  }
#pragma unroll
  for (int fr = 0; fr < 4; ++fr)
#pragma unroll
    for (int fc = 0; fc < 2; ++fc){
      const int col = cbase + wn*32 + fc*16 + lo;
      if (col < NMU){
        const float bv = bias[col];
        const int r0 = rbase + wm*64 + fr*16 + hi4*4;
#pragma unroll
        for (int j = 0; j < 4; ++j)
          C[(long)(r0 + j) * NMU + col] = acc[fr][fc][j] + bv;
      }
    }
}

// ---------------- stage-1 W pack: 3-way bf16 split, fragment-ready ----------
__global__ __launch_bounds__(256) void k_pack_w3(
    const float* __restrict__ W, unsigned short* __restrict__ Wb3)
{
  const int g = blockIdx.x * 256 + threadIdx.x;   // 16*3*64*80
  if (g >= 245760) return;
  const int k4 = g % 80;
  const int r2 = g / 80;
  const int row = r2 % 64;
  const int r3 = r2 / 64;
  const int s = r3 % 3;
  const int js = r3 / 3;
  const int wid = (js < 15) ? 19 : 15;
  const int jj0 = js * 19;
  unsigned short o4[4];
#pragma unroll
  for (int e = 0; e < 4; ++e){
    const int k = k4 * 4 + e;
    float v = 0.0f;
    if (row < 3 * wid && k < 300){
      const int gate = row / wid, col = row - gate * wid;
      v = W[(long)(gate * 300 + jj0 + col) * 300 + k];
    }
    const unsigned short w1 = f2bf(v);
    const float r1 = v - bf2f(w1);
    const unsigned short w2 = f2bf(r1);
    const float r2f = r1 - bf2f(w2);
    const unsigned short w3 = f2bf(r2f);
    o4[e] = (s == 0) ? w1 : ((s == 1) ? w2 : w3);
  }
  *(uint2*)(Wb3 + ((long)(js * 3 + s) * 64 + row) * 320 + k4 * 4) = *(const uint2*)o4;
}

// ---------------- stage-1: 256 blocks = 16 batch-groups(8 rows) x 16 jj-slices --
// Writes split-bf16(relu(h)) DIRECTLY into the mu-GEMM A matrix (hx half) —
// hx_all round-trip eliminated. Values bit-identical to the old cvt pass.
#define S1PAD 304

__global__ __launch_bounds__(256, 1) void k_stage1(
    const unsigned short* __restrict__ Wb3, const float* __restrict__ bhh,
    const float* __restrict__ gi_all,
    unsigned short* __restrict__ AmH, unsigned short* __restrict__ AmL,
    float* __restrict__ hex, unsigned int* __restrict__ flagsA)
{
  __shared__ __align__(16) float hs[8][S1PAD];
  __shared__ __align__(16) unsigned short hb[3][8][320];
  __shared__ float ghs[512];
  const int tid = threadIdx.x;
  const int bid = blockIdx.x;
  const int bq = bid >> 4, js = bid & 15;
  const int b0 = bq * 8;
  const int wid = (js < 15) ? 19 : 15;
  const int jj0 = js * 19;
  const int NC = 3 * wid;

  const int wave = tid >> 6, lane = tid & 63;
  const int lo = lane & 15, hi = lane >> 4;

  using frag = __attribute__((ext_vector_type(8))) short;
  using f32x4v = __attribute__((ext_vector_type(4))) float;

  frag wfr[3][10];
  {
    const int row = wave * 16 + lo;
#pragma unroll
    for (int s = 0; s < 3; ++s)
#pragma unroll
      for (int kf = 0; kf < 10; ++kf)
        wfr[s][kf] = *(const frag*)(Wb3 + ((long)(js * 3 + s) * 64 + row) * 320
                                         + kf * 32 + hi * 8);
  }

  const bool gact = tid < 8 * wid;
  const int grow = gact ? (tid / wid) : 0;
  const int gcol = gact ? (tid - grow * wid) : 0;
  const int gjj = jj0 + gcol;
  float bhr = 0.f, bhz = 0.f, bhn = 0.f;
  if (gact){ bhr = bhh[gjj]; bhz = bhh[DD + gjj]; bhn = bhh[2*DD + gjj]; }

  for (int i = tid; i < 8 * S1PAD; i += 256) ((float*)hs)[i] = 0.f;
  for (int i = tid; i < 3840; i += 256) ((unsigned int*)hb)[i] = 0u;
  __syncthreads();

  unsigned int* myflag = flagsA + bid * 16;

  for (int t = 0; t < TT; ++t){
    float gir = 0.f, giz = 0.f, gin = 0.f;
    if (gact){
      const float* gp = gi_all + ((long)t * BB + b0 + grow) * GG;
      gir = gp[gjj]; giz = gp[DD + gjj]; gin = gp[2*DD + gjj];
    }

    f32x4v a0 = {0,0,0,0}, a1 = {0,0,0,0}, a2 = {0,0,0,0};
#pragma unroll
    for (int kf = 0; kf < 10; ++kf){
      frag h1 = *(const frag*)&hb[0][lo & 7][kf * 32 + hi * 8];
      frag h2 = *(const frag*)&hb[1][lo & 7][kf * 32 + hi * 8];
      frag h3 = *(const frag*)&hb[2][lo & 7][kf * 32 + hi * 8];
      a0 = __builtin_amdgcn_mfma_f32_16x16x32_bf16(h1, wfr[0][kf], a0, 0, 0, 0);
      a1 = __builtin_amdgcn_mfma_f32_16x16x32_bf16(h1, wfr[1][kf], a1, 0, 0, 0);
      a2 = __builtin_amdgcn_mfma_f32_16x16x32_bf16(h1, wfr[2][kf], a2, 0, 0, 0);
      a0 = __builtin_amdgcn_mfma_f32_16x16x32_bf16(h2, wfr[0][kf], a0, 0, 0, 0);
      a1 = __builtin_amdgcn_mfma_f32_16x16x32_bf16(h2, wfr[1][kf], a1, 0, 0, 0);
      a2 = __builtin_amdgcn_mfma_f32_16x16x32_bf16(h2, wfr[2][kf], a2, 0, 0, 0);
      a0 = __builtin_amdgcn_mfma_f32_16x16x32_bf16(h3, wfr[0][kf], a0, 0, 0, 0);
      a1 = __builtin_amdgcn_mfma_f32_16x16x32_bf16(h3, wfr[1][kf], a1, 0, 0, 0);
      a2 = __builtin_amdgcn_mfma_f32_16x16x32_bf16(h3, wfr[2][kf], a2, 0, 0, 0);
    }
    {
      const int nc = wave * 16 + lo;
      if (hi < 2 && nc < NC){
#pragma unroll
        for (int j = 0; j < 4; ++j)
          ghs[nc * 8 + hi * 4 + j] = (a0[j] + a1[j]) + a2[j];
      }
    }
    __syncthreads();

    const int par = t & 1;
    if (gact){
      const float r = jsigmoid(gir + ghs[(0 * wid + gcol) * 8 + grow] + bhr);
      const float z = jsigmoid(giz + ghs[(1 * wid + gcol) * 8 + grow] + bhz);
      const float n = tanhf(gin + r * (ghs[(2 * wid + gcol) * 8 + grow] + bhn));
      const float hn = (1.0f - z) * n + z * hs[grow][gjj];
      // mu-A hx half: split-bf16(relu(hn)) direct
      {
        const long amoff = ((long)t * BB + b0 + grow) * KP + 300 + gjj;
        const float hr = fmaxf(hn, 0.0f);
        const unsigned short h1s = f2bf(hr);
        AmH[amoff] = h1s;
        AmL[amoff] = f2bf(hr - bf2f(h1s));
      }
      if (t < TT - 1)
        store_u32_llc(hex + ((long)par * BB + b0 + grow) * S1PAD + gjj,
                      __float_as_uint(hn));
    }

    if (t < TT - 1){
      asm volatile("s_waitcnt vmcnt(0)" ::: "memory");
      __syncthreads();
      if (tid == 0) store_u32_llc(myflag, (unsigned)(t + 1));
      if (tid < 16){
        const unsigned int* fp = flagsA + (bq * 16 + tid) * 16;
        unsigned v = poll_u32_llc(fp);
        while (v < (unsigned)(t + 1)){
          __builtin_amdgcn_s_sleep(1);
          v = poll_u32_llc(fp);
        }
      }
      __syncthreads();
      {
        const float* src = hex + (long)par * BB * S1PAD + (long)b0 * S1PAD;
        const int gA = tid, gB = tid + 256, gC = tid + 512;
        const int rA = gA / 76, cA = gA - rA * 76;
        const int rB = gB / 76, cB = gB - rB * 76;
        int rC = 0, cC = 0;
        u32x4 vA = load_b128_llc(src + (long)rA * S1PAD + cA * 4);
        u32x4 vB = load_b128_llc(src + (long)rB * S1PAD + cB * 4);
        u32x4 vC = (u32x4){0,0,0,0};
        if (gC < 608){
          rC = gC / 76; cC = gC - rC * 76;
          vC = load_b128_llc(src + (long)rC * S1PAD + cC * 4);
        }
        WAITV(0);
#define CONV_STORE(rr, cc, vv) do{ \
        float f0 = __uint_as_float(vv[0]), f1 = __uint_as_float(vv[1]); \
        float f2v = __uint_as_float(vv[2]), f3 = __uint_as_float(vv[3]); \
        if ((cc) == 75){ f0 = 0.f; f1 = 0.f; f2v = 0.f; f3 = 0.f; } \
        *(u32x4*)&hs[rr][(cc) * 4] = vv; \
        float fv[4] = {f0, f1, f2v, f3}; \
        unsigned short s1[4], s2[4], s3[4]; \
        _Pragma("unroll") \
        for (int j = 0; j < 4; ++j){ \
          s1[j] = f2bf(fv[j]); \
          const float r1 = fv[j] - bf2f(s1[j]); \
          s2[j] = f2bf(r1); \
          s3[j] = f2bf(r1 - bf2f(s2[j])); \
        } \
        *(uint2*)&hb[0][rr][(cc) * 4] = *(const uint2*)s1; \
        *(uint2*)&hb[1][rr][(cc) * 4] = *(const uint2*)s2; \
        *(uint2*)&hb[2][rr][(cc) * 4] = *(const uint2*)s3; \
      }while(0)
        CONV_STORE(rA, cA, vA);
        CONV_STORE(rB, cB, vB);
        if (gC < 608) CONV_STORE(rC, cC, vC);
#undef CONV_STORE
      }
      __syncthreads();
    }
  }
}

// ---------------- sampling (texts written in MFMA-fragment order) ------------
__global__ __launch_bounds__(256) void k_sample(
    const float* __restrict__ X, const float* __restrict__ mu_all,
    unsigned short* __restrict__ tF, float* __restrict__ out,
    const uint32_t k0a, const uint32_t k0b, const uint32_t k1a, const uint32_t k1b,
    const uint32_t k2a, const uint32_t k2b, const uint32_t k3a, const uint32_t k3b)
{
  const int r = blockIdx.x;            // t*128 + b
  const int t = r >> 7, b = r & 127;
  const int tid = threadIdx.x;
  const int h = tid >> 7, lane = tid & 127;
  const int wv = tid >> 6;
  __shared__ float redw[4];
  __shared__ int   redi4[4];
  __shared__ float yw[2], lyw[2], att_s[2];

  const uint32_t rowbase = (uint32_t)((t * 256 + b * 2 + h) * 500);
  float zv[4], ev[4];
  float lmax = -3.0e38f;
#pragma unroll
  for (int s = 0; s < 4; ++s){
    const int a = lane + s * 128;
    float z = -3.0e38f;
    if (a < ASP){
      float g = jgumbel(k0a, k0b, rowbase + (uint32_t)a);
      float m = mu_all[(long)r * NMU + h * ASP + a];
      z = (m + g) / 0.8f;
    }
    zv[s] = z;
    lmax = fmaxf(lmax, z);
  }
  {
    float wm = lmax;
#pragma unroll
    for (int o = 32; o > 0; o >>= 1) wm = fmaxf(wm, __shfl_xor(wm, o));
    if ((tid & 63) == 0) redw[wv] = wm;
  }
  __syncthreads();
  const float mx = fmaxf(redw[h * 2], redw[h * 2 + 1]);
  __syncthreads();

  float lsum = 0.0f;
#pragma unroll
  for (int s = 0; s < 4; ++s){
    const int a = lane + s * 128;
    float e = 0.0f;
    if (a < ASP) e = expf(zv[s] - mx);
    ev[s] = e;
    lsum += e;
  }
  {
    float wsum = lsum;
#pragma unroll
    for (int o = 32; o > 0; o >>= 1) wsum += __shfl_xor(wsum, o);
    if ((tid & 63) == 0) redw[wv] = wsum;
  }
  __syncthreads();
  const float S = redw[h * 2] + redw[h * 2 + 1];
  __syncthreads();

  float bestv = -3.0e38f;
  int besti = 0x7fffffff;
#pragma unroll
  for (int s = 0; s < 4; ++s){
    const int a = lane + s * 128;
    if (a < ASP){
      float y = ev[s] / S;
      float ly = logf(y);
      float gc = jgumbel(k1a, k1b, rowbase + (uint32_t)a);
      float val = ly + gc;
      if (val > bestv){ bestv = val; besti = a; }
    }
  }
  {
    float bv = bestv; int bi = besti;
#pragma unroll
    for (int o = 32; o > 0; o >>= 1){
      float v2 = __shfl_xor(bv, o);
      int   i2 = __shfl_xor(bi, o);
      if (v2 > bv || (v2 == bv && i2 < bi)){ bv = v2; bi = i2; }
    }
    if ((tid & 63) == 0){ redw[wv] = bv; redi4[wv] = bi; }
  }
  __syncthreads();
  int ind;
  {
    const float v0 = redw[h * 2], v1 = redw[h * 2 + 1];
    const int   i0 = redi4[h * 2], i1 = redi4[h * 2 + 1];
    ind = (v1 > v0 || (v1 == v0 && i1 < i0)) ? i1 : i0;
  }
#pragma unroll
  for (int s = 0; s < 4; ++s){
    const int a = lane + s * 128;
    if (a == ind){
      float y = ev[s] / S;
      yw[h] = y;
      lyw[h] = logf(y);
    }
  }
  __syncthreads();
  if (lane == 0){
    const float yv = yw[h];
    const float ly = lyw[h];
    const float yh = (1.0f - yv) + yv;
    const float act = ((float)ind * yh) / 500.0f;
    const float lvr = mu_all[(long)r * NMU + 1000 + h];
    const float lv = fmaxf(lvr, 0.0f) + log1pf(expf(-fabsf(lvr)));
    const float sd = expf(0.5f * lv);
    const uint32_t ei = (uint32_t)(r * 2 + h);
    const float e1 = jnormal(k2a, k2b, ei);
    const float e2 = jnormal(k3a, k3b, ei);
    const float s1 = act + sd * e1;
    const float s2 = act + sd * e2;
    const float dd = (s2 - act) / sd;
    const float lp = -0.5f * (dd * dd) - logf(sd) - 0.9189385332046727f;
    const float attv = 20.0f * jsigmoid(s1);
    out[OUT_SLOG + (long)b * 256 + t * 2 + h]  = ly;
    out[OUT_ACT  + (long)b * 256 + h * 128 + t] = act;
    out[OUT_LOGP + (long)b * 256 + h * 128 + t] = lp;
    att_s[h] = attv;
  }
  __syncthreads();
  const float* xr = X + ((long)b * TT + t) * DD;
  if (tid < 40){
    unsigned short pk[8];
#pragma unroll
    for (int e = 0; e < 8; ++e){
      const int idx = tid * 8 + e;
      float v = 0.0f;
      if (idx < 300) v = xr[idx] * att_s[idx / 150];
      pk[e] = f2bf(v);
    }
    unsigned short* dst = tF + (((long)t * 8 + (b >> 4)) * 40 + tid) * 128
                             + (b & 15) * 8;
    *(uint4*)dst = *(const uint4*)pk;
  }
}

// ---------------- weight conversion to bf16 (stage-2) ----------------
__global__ __launch_bounds__(256) void k_cvt_whh(
    const float* __restrict__ W, unsigned short* __restrict__ O)
{
  const int i = blockIdx.x * 256 + threadIdx.x;   // 3072*1024
  O[i] = f2bf(W[i]);
}

__global__ __launch_bounds__(256) void k_cvt_wih(
    const float* __restrict__ W, unsigned short* __restrict__ O)
{
  const int i = blockIdx.x * 256 + threadIdx.x;   // 3072*320
  const int rw = i / 320, c = i - rw * 320;
  O[i] = (c < DD) ? f2bf(W[(long)rw * DD + c]) : (unsigned short)0;
}

// ---------------- stage-2 persistent: 128 blocks x 512 thr (R17/R19) ----------
#define NBLK2 128
#define WPITCH 2704   // 1344*2 + 16

__global__ __launch_bounds__(512) void k_stage2(
    const unsigned short* __restrict__ tF,
    const unsigned short* __restrict__ Whb,
    const unsigned short* __restrict__ Wib,
    const float* __restrict__ bih, const float* __restrict__ bhh,
    const int* __restrict__ lengths,
    unsigned short* __restrict__ hF0, unsigned short* __restrict__ hF1,
    float* __restrict__ last,
    unsigned int* __restrict__ flags)
{
  __shared__ __align__(16) char lds[152320];   // W:129792 | reduce:20480 | Tl:2048
  unsigned short* Wl = (unsigned short*)lds;
  char* Al = lds + 129792;
  unsigned short* Tl = (unsigned short*)(lds + 150272);

  const int tid = threadIdx.x;
  const int bid = blockIdx.x;
  const int m = bid >> 6, n = bid & 63;
  const int e0 = n * 16, mrow = m * 64;
  const int wave = tid >> 6, wg = wave >> 2, wvr = wave & 3;
  const int lane = tid & 63, lo = lane & 15, hi = lane >> 4;
  const int tidg = tid & 255;

  for (int s = tid; s < 48 * 168; s += 512){
    const int row = s / 168, q = s - row * 168;
    const int g = row >> 4, nn = row & 15;
    const long wrow = (long)g * EE + e0 + nn;
    uint4 v;
    if (q < 128) v = *(const uint4*)(Whb + wrow * EE + q * 8);
    else         v = *(const uint4*)(Wib + wrow * 320 + (q - 128) * 8);
    *(uint4*)((char*)Wl + (long)row * WPITCH + q * 16) = v;
  }

  const int e = e0 + lo;
  const float bR = bih[e] + bhh[e];
  const float bZ = bih[EE + e] + bhh[EE + e];
  const float biN = bih[2*EE + e];
  const float bhN = bhh[2*EE + e];
  int li[4]; float hp[4];
#pragma unroll
  for (int j = 0; j < 4; ++j){
    const int brow = wvr * 16 + hi * 4 + j;
    int l = lengths[mrow + brow] - 1; if (l < 0) l += TT;
    li[j] = l; hp[j] = 0.0f;
  }
  __syncthreads();

  using frag = __attribute__((ext_vector_type(8))) short;
  using f32x4 = __attribute__((ext_vector_type(4))) float;

  const int rg = m * 4 + wvr;
  int boff[3];
#pragma unroll
  for (int g = 0; g < 3; ++g) boff[g] = (g * 16 + lo) * WPITCH + hi * 16;

  const long tBase = ((long)rg * 40 + (wg ? 24 : 0) + hi) * 128 + lo * 8;
  const long hBase = (long)rg * 16384 + (long)(wg * 64 + hi) * 128 + lo * 8;

  unsigned int* flagp = flags + (m << 6) + n;

  for (int t = 0; t < TT; ++t){
    const unsigned short* hFin = (t & 1) ? hF1 : hF0;
    unsigned short* hFout = (t & 1) ? hF0 : hF1;
    const unsigned short* tA = tF + (long)t * 8 * 40 * 128 + tBase;
    const unsigned short* hA = hFin + hBase;

    f32x4 aR = {0,0,0,0}, aZ = {0,0,0,0}, aNH = {0,0,0,0}, aNI = {0,0,0,0};

    auto chunkD = [&](int cc, u32x4 a0v, u32x4 a1v, bool hid){
      frag a0 = *(frag*)&a0v;
      frag a1 = *(frag*)&a1v;
      const char* wb = (const char*)Wl + cc * 128;
      frag b00 = *(const frag*)(wb + boff[0]);
      frag b10 = *(const frag*)(wb + boff[1]);
      frag b20 = *(const frag*)(wb + boff[2]);
      frag b01 = *(const frag*)(wb + boff[0] + 64);
      frag b11 = *(const frag*)(wb + boff[1] + 64);
      frag b21 = *(const frag*)(wb + boff[2] + 64);
      aR = __builtin_amdgcn_mfma_f32_16x16x32_bf16(a0, b00, aR, 0, 0, 0);
      aZ = __builtin_amdgcn_mfma_f32_16x16x32_bf16(a0, b10, aZ, 0, 0, 0);
      if (hid) aNH = __builtin_amdgcn_mfma_f32_16x16x32_bf16(a0, b20, aNH, 0, 0, 0);
      else     aNI = __builtin_amdgcn_mfma_f32_16x16x32_bf16(a0, b20, aNI, 0, 0, 0);
      aR = __builtin_amdgcn_mfma_f32_16x16x32_bf16(a1, b01, aR, 0, 0, 0);
      aZ = __builtin_amdgcn_mfma_f32_16x16x32_bf16(a1, b11, aZ, 0, 0, 0);
      if (hid) aNH = __builtin_amdgcn_mfma_f32_16x16x32_bf16(a1, b21, aNH, 0, 0, 0);
      else     aNI = __builtin_amdgcn_mfma_f32_16x16x32_bf16(a1, b21, aNI, 0, 0, 0);
    };

    {
      u32x4 t0a = load_b128_llc(tA);
      u32x4 t0b = load_b128_llc(tA + 512);
      u32x4 t1a = load_b128_llc(tA + 1024);
      u32x4 t1b = load_b128_llc(tA + 1536);
      if (wg == 0){
        u32x4 t2a = load_b128_llc(tA + 2048);
        u32x4 t2b = load_b128_llc(tA + 2560);
        WAITV(4); chunkD(16, t0a, t0b, false);
        WAITV(2); chunkD(17, t1a, t1b, false);
        WAITV(0); chunkD(18, t2a, t2b, false);
      } else {
        WAITV(2); chunkD(19, t0a, t0b, false);
        WAITV(0); chunkD(20, t1a, t1b, false);
      }
    }

    if (t > 0){
      if (tid < 16){
        const unsigned int* fp = flags + (m << 6) + tid * 4;
        for (;;){
          u32x4 f = load_b128_llc(fp);
          WAITV(0);
          if (f[0] >= (unsigned)t && f[1] >= (unsigned)t &&
              f[2] >= (unsigned)t && f[3] >= (unsigned)t) break;
          __builtin_amdgcn_s_sleep(2);
        }
      }
      __syncthreads();

      u32x4 h0a = load_b128_llc(hA +    0), h0b = load_b128_llc(hA +  512);
      u32x4 h1a = load_b128_llc(hA + 1024), h1b = load_b128_llc(hA + 1536);
      u32x4 h2a = load_b128_llc(hA + 2048), h2b_ = load_b128_llc(hA + 2560);
      u32x4 h3a = load_b128_llc(hA + 3072), h3b = load_b128_llc(hA + 3584);
      u32x4 h4a = load_b128_llc(hA + 4096), h4b = load_b128_llc(hA + 4608);
      u32x4 h5a = load_b128_llc(hA + 5120), h5b = load_b128_llc(hA + 5632);
      u32x4 h6a = load_b128_llc(hA + 6144), h6b = load_b128_llc(hA + 6656);
      u32x4 h7a = load_b128_llc(hA + 7168), h7b = load_b128_llc(hA + 7680);
      const int cb = wg * 8;
      WAITV(14); chunkD(cb + 0, h0a, h0b, true);
      WAITV(12); chunkD(cb + 1, h1a, h1b, true);
      WAITV(10); chunkD(cb + 2, h2a, h2b_, true);
      WAITV(8);  chunkD(cb + 3, h3a, h3b, true);
      WAITV(6);  chunkD(cb + 4, h4a, h4b, true);
      WAITV(4);  chunkD(cb + 5, h5a, h5b, true);
      WAITV(2);  chunkD(cb + 6, h6a, h6b, true);
      WAITV(0);  chunkD(cb + 7, h7a, h7b, true);
    }

    __syncthreads();
    if (wg == 1){
      char* dst = Al + tidg * 80;
      *(f32x4*)(dst)      = aR;
      *(f32x4*)(dst + 16) = aZ;
      *(f32x4*)(dst + 32) = aNH;
      *(f32x4*)(dst + 48) = aNI;
    }
    __syncthreads();
    if (wg == 0){
      const char* src = Al + tidg * 80;
      const f32x4 pR  = *(const f32x4*)(src);
      const f32x4 pZ  = *(const f32x4*)(src + 16);
      const f32x4 pNH = *(const f32x4*)(src + 32);
      const f32x4 pNI = *(const f32x4*)(src + 48);
#pragma unroll
      for (int j = 0; j < 4; ++j){
        aR[j] += pR[j]; aZ[j] += pZ[j]; aNH[j] += pNH[j]; aNI[j] += pNI[j];
      }
#pragma unroll
      for (int j = 0; j < 4; ++j){
        const int brow = wvr * 16 + hi * 4 + j;
        const float r = jsigmoid(aR[j] + bR);
        const float z = jsigmoid(aZ[j] + bZ);
        const float nn2 = tanhf(aNI[j] + biN + r * (aNH[j] + bhN));
        const float hn = (1.0f - z) * nn2 + z * hp[j];
        hp[j] = hn;
        Tl[brow * 16 + lo] = f2bf(hn);
        if (t == li[j]) last[(long)(mrow + brow) * EE + e] = hn;
      }
    }

    if (t < TT - 1){
      __syncthreads();
      if (tid < 128){
        const int rgp = tid >> 5;
        const int kbp = (tid >> 4) & 1;
        const int lop = tid & 15;
        u32x4 v = *(const u32x4*)(Tl + (rgp * 16 + lop) * 16 + kbp * 8);
        store_b128_llc(hFout + ((long)(m * 4 + rgp) * 128 + (n * 2 + kbp)) * 128
                             + lop * 8, v);
      }
      asm volatile("s_waitcnt vmcnt(0)" ::: "memory");
      __syncthreads();
      if (tid == 0) store_u32_llc(flagp, (unsigned)(t + 1));
    }
  }
}

// ---------------- BatchNorm ----------------
__global__ __launch_bounds__(256) void k_bn_stats(
    const float* __restrict__ last, float* __restrict__ mv)
{
  const int e = blockIdx.x * 256 + threadIdx.x;
  if (e >= EE) return;
  float s = 0.0f;
  for (int b = 0; b < BB; ++b) s += last[(long)b * EE + e];
  const float mean = s / 128.0f;
  float v = 0.0f;
  for (int b = 0; b < BB; ++b){ float d = last[(long)b * EE + e] - mean; v += d * d; }
  mv[e] = mean;
  mv[EE + e] = v / 128.0f;
}

__global__ __launch_bounds__(256) void k_bn_apply(
    const float* __restrict__ last, const float* __restrict__ mv,
    const float* __restrict__ gamma, const float* __restrict__ beta,
    float* __restrict__ out)
{
  const int gid = blockIdx.x * 256 + threadIdx.x;
  const int e = gid & 1023;
  const float xm = last[gid] - mv[e];
  out[gid] = gamma[e] * xm / sqrtf(mv[EE + e] + 1e-5f) + beta[e];
}

// ---------------- launcher ----------------
extern "C" void kernel_launch(void* const* d_in, const int* in_sizes, int n_in,
                              void* d_out, int out_size, void* d_ws, size_t ws_size,
                              hipStream_t stream)
{
  (void)in_sizes; (void)n_in; (void)out_size;
  const float* x     = (const float*)d_in[0];
  const int*   lens  = (const int*)d_in[1];
  const float* Wih_c = (const float*)d_in[3];
  const float* Whh_c = (const float*)d_in[4];
  const float* bih_c = (const float*)d_in[5];
  const float* bhh_c = (const float*)d_in[6];
  const float* Wmu   = (const float*)d_in[7];
  const float* bmu   = (const float*)d_in[8];
  const float* Wlv   = (const float*)d_in[9];
  const float* blv   = (const float*)d_in[10];
  const float* Wih_r = (const float*)d_in[11];
  const float* Whh_r = (const float*)d_in[12];
  const float* bih_r = (const float*)d_in[13];
  const float* bhh_r = (const float*)d_in[14];
  const float* gam   = (const float*)d_in[15];
  const float* bet   = (const float*)d_in[16];
  float* out = (float*)d_out;

  uint32_t nk[4][2];
  for (uint32_t i = 0; i < 4; ++i) tf2x32(0u, 42u, 0u, i, &nk[i][0], &nk[i][1]);

  float* ws = (float*)d_ws;
  size_t off = 0;
  float* U       = ws + off; off += 16515072;  // gi_all then mu_all[16384][1008]
  float* lastb   = ws + off; off += 131072;
  float* mv      = ws + off; off += 2048;
  float* hex     = ws + off; off += 77824;     // [2][128][304] f32 stage-1 exchange
  float* biasM   = ws + off; off += 1024;      // fused mu+lv bias
  unsigned int* flags  = (unsigned int*)(ws + off); off += 2048;  // stage-2 packed [m][64]
  unsigned int* flagsA = (unsigned int*)(ws + off); off += 4096;  // stage-1: 256*16
  unsigned short* tF  = (unsigned short*)(ws + off); off += 2621440; // texts frag order
  unsigned short* hF0 = (unsigned short*)(ws + off); off += 65536;
  unsigned short* hF1 = (unsigned short*)(ws + off); off += 65536;
  unsigned short* Whb = (unsigned short*)(ws + off); off += 1572864; // 3072x1024 bf16
  unsigned short* Wib = (unsigned short*)(ws + off); off += 491520;  // 3072x320 bf16
  unsigned short* Wb3 = (unsigned short*)(ws + off); off += 491520;  // [16][3][64][320] bf16
  unsigned short* WmH = (unsigned short*)(ws + off); off += 311296;  // 1024x608 bf16
  unsigned short* WmL = (unsigned short*)(ws + off); off += 311296;
  unsigned short* AmH = (unsigned short*)(ws + off); off += 4980736; // 16384x608 bf16
  unsigned short* AmL = (unsigned short*)(ws + off); off += 4980736;
  unsigned short* AgH = (unsigned short*)(ws + off); off += 2621440; // 16384x320 bf16
  unsigned short* AgL = (unsigned short*)(ws + off); off += 2621440;
  unsigned short* WgH = (unsigned short*)(ws + off); off += 153600;  // 960x320 bf16
  unsigned short* WgL = (unsigned short*)(ws + off); off += 153600;
  if (ws_size < off * sizeof(float)) return;

  hipMemsetAsync(flags, 0, 2048 * sizeof(unsigned int), stream);
  hipMemsetAsync(flagsA, 0, 4096 * sizeof(unsigned int), stream);

  // weight prep
  k_cvt_whh<<<dim3(12288), 256, 0, stream>>>(Whh_r, Whb);
  k_cvt_wih<<<dim3(3840), 256, 0, stream>>>(Wih_r, Wib);
  k_pack_w3<<<dim3(960), 256, 0, stream>>>(Whh_c, Wb3);
  k_cvt_Wmu<<<dim3(608), 256, 0, stream>>>(Wmu, Wlv, WmH, WmL);
  k_bias_mu<<<dim3(4), 256, 0, stream>>>(bmu, blv, biasM);
  k_cvt_Wgi<<<dim3(300), 256, 0, stream>>>(Wih_c, WgH, WgL);

  // merged x conversions (gi A + mu A x-half)
  k_cvt_Axm<<<dim3(5120), 256, 0, stream>>>(x, AgH, AgL, AmH, AmL);

  // stage-1 input projection (split-bf16 MFMA) + persistent MFMA recurrence
  // (stage-1 writes the mu-A hx half directly)
  k_gemm_gf<<<dim3(15, 128), 256, 0, stream>>>(AgH, AgL, WgH, WgL, bih_c, U);
  k_stage1<<<dim3(256), 256, 0, stream>>>(Wb3, bhh_c, U, AmH, AmL, hex, flagsA);

  // mu+lv via split-bf16 4-term MFMA, then sampling
  k_gemm_mf<<<dim3(16, 128), 256, 0, stream>>>(AmH, AmL, WmH, WmL, biasM, U);
  k_sample<<<dim3(16384), 256, 0, stream>>>(x, U, tF, out,
      nk[0][0], nk[0][1], nk[1][0], nk[1][1],
      nk[2][0], nk[2][1], nk[3][0], nk[3][1]);

  // stage-2 persistent recurrence (R17 schedule: frag-ordered A, B LDS-resident)
  k_stage2<<<dim3(NBLK2), 512, 0, stream>>>(tF, Whb, Wib, bih_r, bhh_r, lens,
                                            hF0, hF1, lastb, flags);

  // batchnorm
  k_bn_stats<<<dim3(4), 256, 0, stream>>>(lastb, mv);
  k_bn_apply<<<dim3(512), 256, 0, stream>>>(lastb, mv, gam, bet, out);
}